// Round 24
// baseline (312.978 us; speedup 1.0000x reference)
//
#include <hip/hip_runtime.h>
#include <hip/hip_bf16.h>
#include <math.h>

#define NTOT    50000
#define CDIM    128
#define FCHUNK  2714
#define MCH     18
#define NREM    (NTOT - MCH*FCHUNK)   /* 1148 */
#define NCHUNKS 19
#define TOPKN   5
#define INNERD  512
#define BNEPS   1e-5f
#define SEGS    64
#define RPT     8     /* rows per thread (512-thread k2, 64 segs) */
#define CAP     20
#define APAD    136   /* ushort stride, 272B = 17*16 -> b128-aligned rows */
#define WPAD    40    /* ushort stride, 80B = 5*16  -> b128-aligned rows */

typedef __attribute__((ext_vector_type(8))) short short8v;   // 8 bf16 = 4 VGPR
typedef __attribute__((ext_vector_type(4))) float float4v;   // MFMA acc

static __device__ __forceinline__ int chunk_n(int chunk) {
    return (chunk < MCH) ? FCHUNK : NREM;
}

static __device__ __forceinline__ unsigned short bf16hi(float v) {
    return (unsigned short)(__float_as_uint(v) >> 16);   // truncation
}

static __device__ __forceinline__ float bf16tof(unsigned short u) {
    return __uint_as_float((unsigned)u << 16);
}

// strict-> sorted insert == lax.top_k stable tie-break (ascending-j stream)
#define INS5(s, jj, V0,V1,V2,V3,V4,I0,I1,I2,I3,I4) \
    if (s > V4) { \
        if (s > V0)      { V4=V3;I4=I3; V3=V2;I3=I2; V2=V1;I2=I1; V1=V0;I1=I0; V0=s;I0=jj; } \
        else if (s > V1) { V4=V3;I4=I3; V3=V2;I3=I2; V2=V1;I2=I1; V1=s;I1=jj; } \
        else if (s > V2) { V4=V3;I4=I3; V3=V2;I3=I2; V2=s;I2=jj; } \
        else if (s > V3) { V4=V3;I4=I3; V3=s;I3=jj; } \
        else             { V4=s;I4=jj; } \
    }

// composite (val desc, idx asc) insert — order-independent == stable top-k
#define INS5C(s, jj, V0,V1,V2,V3,V4,I0,I1,I2,I3,I4) \
    if ((s > V4) || (s == V4 && jj < I4)) { \
        if ((s > V0) || (s == V0 && jj < I0))      { V4=V3;I4=I3; V3=V2;I3=I2; V2=V1;I2=I1; V1=V0;I1=I0; V0=s;I0=jj; } \
        else if ((s > V1) || (s == V1 && jj < I1)) { V4=V3;I4=I3; V3=V2;I3=I2; V2=V1;I2=I1; V1=s;I1=jj; } \
        else if ((s > V2) || (s == V2 && jj < I2)) { V4=V3;I4=I3; V3=V2;I3=I2; V2=s;I2=jj; } \
        else if ((s > V3) || (s == V3 && jj < I3)) { V4=V3;I4=I3; V3=s;I3=jj; } \
        else                                        { V4=s;I4=jj; } \
    }

#define CAS(x, y) { float lo_ = fminf(x, y), hi_ = fmaxf(x, y); x = lo_; y = hi_; }

// ---- K1: W1 = Wv @ Wo, emit W1^T as bf16 (truncated) [col][k] ----
__global__ void k1_w1(const float* __restrict__ Wv, const float* __restrict__ Wo,
                      unsigned short* __restrict__ Th)
{
    __shared__ float s_wv[INNERD];
    int r = blockIdx.x;
    for (int t = threadIdx.x; t < INNERD; t += blockDim.x) s_wv[t] = Wv[r*INNERD + t];
    __syncthreads();
    int c = threadIdx.x;
    float acc = 0.f;
    #pragma unroll 8
    for (int k = 0; k < INNERD; ++k) acc = fmaf(s_wv[k], Wo[k*CDIM + c], acc);
    Th[c*CDIM + r] = bf16hi(acc);    // transposed: [col][k]
}

// ---- K1b: Wp^T -> bf16 (own buffer; launched up front) ----
__global__ void k1b_wp(const float* __restrict__ Wp, unsigned short* __restrict__ Thp)
{
    int r = blockIdx.x, c = threadIdx.x;
    Thp[c*CDIM + r] = bf16hi(Wp[r*CDIM + c]);
}

// --- K2: top-5; shfl supersegment reduce + compact candidate buf (4 blk/CU) ---
__global__ __launch_bounds__(512) void k2_topk(const float* __restrict__ x_c,
                                               const float* __restrict__ h_c,
                                               int* __restrict__ tidx)
{
    __shared__ float2 s_x01[FCHUNK];
    __shared__ float  s_x2[FCHUNK];
    __shared__ float  scratch[1984];          // A: ssm[64][9]+thr[64] | B: cnt/cv/cj
    int chunk = blockIdx.y;
    int base  = chunk * FCHUNK;
    int n     = chunk_n(chunk);
    int row0  = blockIdx.x * 64;
    if (row0 >= n) return;

    for (int e = threadIdx.x; e < n; e += 512) {
        s_x01[e] = make_float2(x_c[(base+e)*3], x_c[(base+e)*3 + 1]);
        s_x2[e]  = x_c[(base+e)*3 + 2];
    }
    __syncthreads();

    int seg = threadIdx.x & 63;               // residue class: j = seg + 64t
    int g   = threadIdx.x >> 6;               // 0..7; rows g, g+8, ..., g+56
    // NOTE: wave w == g; its 64 lanes are exactly segs 0..63

    float h0[RPT], h1[RPT], h2[RPT];
    #pragma unroll
    for (int r = 0; r < RPT; ++r) {
        int row = row0 + g + 8*r;
        bool v = row < n;
        h0[r] = v ? h_c[(base+row)*3  ] : 0.f;
        h1[r] = v ? h_c[(base+row)*3+1] : 0.f;
        h2[r] = v ? h_c[(base+row)*3+2] : 0.f;
    }

    // ---- pass 1: branchless residue-class maxes, 8 rows per x-read ----
    float m[RPT];
    #pragma unroll
    for (int r = 0; r < RPT; ++r) m[r] = -INFINITY;
    #pragma unroll 2
    for (int j = seg; j < n; j += SEGS) {
        float2 x01 = s_x01[j];
        float  xz  = s_x2[j];
        #pragma unroll
        for (int r = 0; r < RPT; ++r)
            m[r] = fmaxf(m[r], fmaf(xz,h2[r], fmaf(x01.y,h1[r], x01.x*h0[r])));
    }

    // wave-level supersegment-of-8 reduce (identical partition as before)
    float* s_ssm = scratch;                   // [64][9]
    float* s_thr = scratch + 64*9;            // [64]
    #pragma unroll
    for (int r = 0; r < RPT; ++r) {
        float v = m[r];
        v = fmaxf(v, __shfl_xor(v, 1, 64));
        v = fmaxf(v, __shfl_xor(v, 2, 64));
        v = fmaxf(v, __shfl_xor(v, 4, 64));
        if ((seg & 7) == 0) s_ssm[(g + 8*r)*9 + (seg >> 3)] = v;
    }
    __syncthreads();

    // ---- threshold: 5th largest of 8 supersegment maxes (T <= v5) ----
    if (threadIdx.x < 64) {
        int lr = threadIdx.x;
        const float* sm = &s_ssm[lr*9];
        float b0=sm[0],b1=sm[1],b2=sm[2],b3=sm[3],b4=sm[4],b5=sm[5],b6=sm[6],b7=sm[7];
        CAS(b0,b1); CAS(b2,b3); CAS(b4,b5); CAS(b6,b7);
        CAS(b0,b2); CAS(b1,b3); CAS(b4,b6); CAS(b5,b7);
        CAS(b1,b2); CAS(b5,b6);
        CAS(b0,b4); CAS(b1,b5); CAS(b2,b6); CAS(b3,b7);
        CAS(b2,b4); CAS(b3,b5);
        CAS(b1,b2); CAS(b3,b4); CAS(b5,b6);
        s_thr[lr] = (row0 + lr < n) ? b3 : INFINITY;   // ascending[3] = 5th largest
    }
    __syncthreads();
    float thr[RPT];
    #pragma unroll
    for (int r = 0; r < RPT; ++r) thr[r] = s_thr[g + 8*r];
    __syncthreads();

    // overlay phase B: compact candidate buffers (f32 val + u16 idx)
    int*            s_cnt = (int*)scratch;                    // [64]
    float*          s_cv  = scratch + 64;                     // [64][CAP]
    unsigned short* s_cj  = (unsigned short*)(scratch + 64 + 64*CAP); // [64][CAP]
    if (threadIdx.x < 64) s_cnt[threadIdx.x] = 0;
    __syncthreads();

    // ---- pass 2: append candidates >= thr (identical fma order -> exact bits) ----
    #pragma unroll 2
    for (int j = seg; j < n; j += SEGS) {
        float2 x01 = s_x01[j];
        float  xz  = s_x2[j];
        #pragma unroll
        for (int r = 0; r < RPT; ++r) {
            float d = fmaf(xz,h2[r], fmaf(x01.y,h1[r], x01.x*h0[r]));
            if (!(d < thr[r])) {
                int lr = g + 8*r;
                int p = atomicAdd(&s_cnt[lr], 1);
                if (p < CAP) { s_cv[lr*CAP+p] = d; s_cj[lr*CAP+p] = (unsigned short)j; }
            }
        }
    }
    __syncthreads();

    // ---- merge: composite top-5 over ~7 candidates per row ----
    if (threadIdx.x < 64) {
        int lr = threadIdx.x, row = row0 + lr;
        if (row < n) {
            float v0=-INFINITY,v1=-INFINITY,v2=-INFINITY,v3=-INFINITY,v4=-INFINITY;
            int i0=0x7fffffff,i1=0x7fffffff,i2=0x7fffffff,i3=0x7fffffff,i4=0x7fffffff;
            int mcnt = s_cnt[lr];
            if (mcnt <= CAP) {
                for (int t = 0; t < mcnt; ++t) {
                    float s = s_cv[lr*CAP + t]; int jj = (int)s_cj[lr*CAP + t];
                    INS5C(s, jj, v0,v1,v2,v3,v4, i0,i1,i2,i3,i4);
                }
            } else {
                // overflow fallback (P ~ 7e-5/row): serial ascending-j rescan
                float ha = h_c[(base+row)*3], hb = h_c[(base+row)*3+1], hc2 = h_c[(base+row)*3+2];
                v0=v1=v2=v3=v4=-INFINITY; i0=i1=i2=i3=i4=0;
                for (int jj = 0; jj < n; ++jj) {
                    float s = fmaf(s_x2[jj],hc2, fmaf(s_x01[jj].y,hb, s_x01[jj].x*ha));
                    INS5(s, jj, v0,v1,v2,v3,v4, i0,i1,i2,i3,i4);
                }
            }
            int o = (base+row)*TOPKN;
            tidx[o+0]=i0; tidx[o+1]=i1; tidx[o+2]=i2; tidx[o+3]=i3; tidx[o+4]=i4;
        }
    }
}

// ---- K3: gather + hsum -> bf16 MFMA GEMM; 512 thr, col-split waves; A out bf16 ----
__global__ __launch_bounds__(512) void k3_gemm1(const float* __restrict__ x_f,
                         const float* __restrict__ h_f,
                         const int* __restrict__ tidx,
                         const unsigned short* __restrict__ Th,
                         const float* __restrict__ bo, unsigned short* __restrict__ A,
                         float* __restrict__ cstats)
{
    __shared__ unsigned short s_ah[64][APAD];
    __shared__ unsigned short s_wh[128][WPAD];
    __shared__ int s_nb[64][TOPKN];
    __shared__ float s_red[256];
    int chunk = blockIdx.y;
    int base  = chunk * FCHUNK;
    int n     = chunk_n(chunk);
    int row0  = blockIdx.x * 64;
    if (row0 >= n) return;

    if (threadIdx.x < 64*TOPKN) {
        int e = threadIdx.x;
        int r = e / TOPKN, k = e % TOPKN;
        int il = row0 + r;
        int nb = 0;
        if (il < n) {
            int p = il*TOPKN + k;             // faithful tidx.T flatten order
            int q, m;
            if (n == FCHUNK) { q = p / FCHUNK; m = p - q*FCHUNK; }
            else             { q = p / NREM;   m = p - q*NREM; }
            nb = tidx[(base + m)*TOPKN + q];
        }
        s_nb[r][k] = nb;
    }
    __syncthreads();

    // gather + hsum (fp32), truncate to bf16 hi plane
    for (int e = threadIdx.x; e < 64*32; e += 512) {
        int r = e >> 5, c4 = e & 31;
        float4 acc4 = make_float4(0.f,0.f,0.f,0.f);
        int gr = row0 + r;
        if (gr < n) {
            acc4 = *(const float4*)&x_f[(base+gr)*CDIM + c4*4];
            #pragma unroll
            for (int k = 0; k < TOPKN; ++k) {
                float4 h4 = *(const float4*)&h_f[(base + s_nb[r][k])*CDIM + c4*4];
                acc4.x += h4.x; acc4.y += h4.y; acc4.z += h4.z; acc4.w += h4.w;
            }
        }
        uint2 ph;
        ph.x = (unsigned)bf16hi(acc4.x) | ((unsigned)bf16hi(acc4.y) << 16);
        ph.y = (unsigned)bf16hi(acc4.z) | ((unsigned)bf16hi(acc4.w) << 16);
        *(uint2*)&s_ah[r][c4*4] = ph;
    }

    int lane = threadIdx.x & 63;
    int w    = threadIdx.x >> 6;          // wave id 0..7
    int wr   = w & 3;                     // row block (16 rows)
    int wc   = w >> 2;                    // col half (64 cols)
    int lr   = lane & 15, lg = lane >> 4;
    float4v acc[4];
    #pragma unroll
    for (int ct = 0; ct < 4; ++ct) acc[ct] = (float4v){0.f,0.f,0.f,0.f};

    for (int ks = 0; ks < 4; ++ks) {
        __syncthreads();
        {   // stage W-hi tile: 4096 ushorts / 512 thr = 1 uint4 each
            int col = threadIdx.x >> 2, q = threadIdx.x & 3;
            *(uint4*)&s_wh[col][q*8] = *(const uint4*)&Th[col*CDIM + ks*32 + q*8];
        }
        __syncthreads();
        short8v a_h = *(const short8v*)&s_ah[wr*16 + lr][ks*32 + lg*8];
        #pragma unroll
        for (int ct = 0; ct < 4; ++ct) {
            short8v b_h = *(const short8v*)&s_wh[(wc*4 + ct)*16 + lr][lg*8];
            acc[ct] = __builtin_amdgcn_mfma_f32_16x16x32_bf16(a_h, b_h, acc[ct], 0,0,0);
        }
    }

    // epilogue + fused per-chunk stats. C/D: col=lane&15, row=(lane>>4)*4+reg
    float ps[4], ps2[4];
    #pragma unroll
    for (int ct = 0; ct < 4; ++ct) { ps[ct] = 0.f; ps2[ct] = 0.f; }
    #pragma unroll
    for (int ct = 0; ct < 4; ++ct) {
        int gcol = (wc*4 + ct)*16 + lr;
        float b = bo[gcol];
        #pragma unroll
        for (int ri = 0; ri < 4; ++ri) {
            int grow = row0 + wr*16 + lg*4 + ri;
            if (grow < n) {
                float v = acc[ct][ri] + b;
                A[(base+grow)*CDIM + gcol] = bf16hi(v);
                ps[ct] += v; ps2[ct] = fmaf(v, v, ps2[ct]);
            }
        }
    }
    #pragma unroll
    for (int ct = 0; ct < 4; ++ct) {          // reduce over lg within wave
        ps[ct]  += __shfl_xor(ps[ct], 16, 64);  ps[ct]  += __shfl_xor(ps[ct], 32, 64);
        ps2[ct] += __shfl_xor(ps2[ct], 16, 64); ps2[ct] += __shfl_xor(ps2[ct], 32, 64);
    }
    __syncthreads();
    if (threadIdx.x < 256) s_red[threadIdx.x] = 0.f;
    __syncthreads();
    if (lane < 16) {
        #pragma unroll
        for (int ct = 0; ct < 4; ++ct) {
            int gcol = (wc*4 + ct)*16 + lane;
            atomicAdd(&s_red[gcol*2],   ps[ct]);
            atomicAdd(&s_red[gcol*2+1], ps2[ct]);
        }
    }
    __syncthreads();
    if (threadIdx.x < 128) {
        atomicAdd(&cstats[chunk*256 + threadIdx.x],       s_red[threadIdx.x*2]);
        atomicAdd(&cstats[chunk*256 + 128 + threadIdx.x], s_red[threadIdx.x*2+1]);
    }
}

// ---- K5: relu(BN_chunk(A_bf16)) -> bf16 MFMA GEMM; 512 thr; fused gstats ----
__global__ __launch_bounds__(512) void k5_gemm2(const unsigned short* __restrict__ A,
                         const unsigned short* __restrict__ Thp,
                         const float* __restrict__ bp, const float* __restrict__ gamma_a,
                         const float* __restrict__ beta_a, const float* __restrict__ cstats,
                         float* __restrict__ Z, float* __restrict__ gstats)
{
    __shared__ unsigned short s_ah[64][APAD];
    __shared__ unsigned short s_wh[128][WPAD];
    __shared__ float s_sc[CDIM], s_sf[CDIM];
    __shared__ float s_red[256];
    int chunk = blockIdx.y;
    int base  = chunk * FCHUNK;
    int n     = chunk_n(chunk);
    int row0  = blockIdx.x * 64;
    if (row0 >= n) return;

    if (threadIdx.x < CDIM) {
        int c = threadIdx.x;
        float inv_n = 1.f / (float)n;
        float mu  = cstats[chunk*256 + c] * inv_n;
        float var = cstats[chunk*256 + 128 + c] * inv_n - mu*mu;
        float sc  = gamma_a[c] * rsqrtf(var + BNEPS);
        s_sc[c] = sc;
        s_sf[c] = beta_a[c] - mu*sc;
    }
    __syncthreads();

    for (int e = threadIdx.x; e < 64*32; e += 512) {
        int r = e >> 5, c4 = e & 31;
        uint2 ph = make_uint2(0u, 0u);
        int gr = row0 + r;
        if (gr < n) {
            uint2 a2 = *(const uint2*)&A[(base+gr)*CDIM + c4*4];
            int c = c4*4;
            float a0 = bf16tof((unsigned short)(a2.x & 0xFFFF));
            float a1 = bf16tof((unsigned short)(a2.x >> 16));
            float a2f = bf16tof((unsigned short)(a2.y & 0xFFFF));
            float a3 = bf16tof((unsigned short)(a2.y >> 16));
            float y0 = fmaxf(fmaf(a0, s_sc[c+0], s_sf[c+0]), 0.f);
            float y1 = fmaxf(fmaf(a1, s_sc[c+1], s_sf[c+1]), 0.f);
            float y2 = fmaxf(fmaf(a2f, s_sc[c+2], s_sf[c+2]), 0.f);
            float y3 = fmaxf(fmaf(a3, s_sc[c+3], s_sf[c+3]), 0.f);
            ph.x = (unsigned)bf16hi(y0) | ((unsigned)bf16hi(y1) << 16);
            ph.y = (unsigned)bf16hi(y2) | ((unsigned)bf16hi(y3) << 16);
        }
        *(uint2*)&s_ah[r][c4*4] = ph;
    }

    int lane = threadIdx.x & 63;
    int w    = threadIdx.x >> 6;
    int wr   = w & 3;
    int wc   = w >> 2;
    int lr   = lane & 15, lg = lane >> 4;
    float4v acc[4];
    #pragma unroll
    for (int ct = 0; ct < 4; ++ct) acc[ct] = (float4v){0.f,0.f,0.f,0.f};

    for (int ks = 0; ks < 4; ++ks) {
        __syncthreads();
        {
            int col = threadIdx.x >> 2, q = threadIdx.x & 3;
            *(uint4*)&s_wh[col][q*8] = *(const uint4*)&Thp[col*CDIM + ks*32 + q*8];
        }
        __syncthreads();
        short8v a_h = *(const short8v*)&s_ah[wr*16 + lr][ks*32 + lg*8];
        #pragma unroll
        for (int ct = 0; ct < 4; ++ct) {
            short8v b_h = *(const short8v*)&s_wh[(wc*4 + ct)*16 + lr][lg*8];
            acc[ct] = __builtin_amdgcn_mfma_f32_16x16x32_bf16(a_h, b_h, acc[ct], 0,0,0);
        }
    }

    float ps[4], ps2[4];
    #pragma unroll
    for (int ct = 0; ct < 4; ++ct) { ps[ct] = 0.f; ps2[ct] = 0.f; }
    #pragma unroll
    for (int ct = 0; ct < 4; ++ct) {
        int gcol = (wc*4 + ct)*16 + lr;
        float b = bp[gcol];
        #pragma unroll
        for (int ri = 0; ri < 4; ++ri) {
            int grow = row0 + wr*16 + lg*4 + ri;
            if (grow < n) {
                float v = acc[ct][ri] + b;
                Z[(base+grow)*CDIM + gcol] = v;
                ps[ct] += v; ps2[ct] = fmaf(v, v, ps2[ct]);
            }
        }
    }
    #pragma unroll
    for (int ct = 0; ct < 4; ++ct) {
        ps[ct]  += __shfl_xor(ps[ct], 16, 64);  ps[ct]  += __shfl_xor(ps[ct], 32, 64);
        ps2[ct] += __shfl_xor(ps2[ct], 16, 64); ps2[ct] += __shfl_xor(ps2[ct], 32, 64);
    }
    __syncthreads();
    if (threadIdx.x < 256) s_red[threadIdx.x] = 0.f;
    __syncthreads();
    if (lane < 16) {
        #pragma unroll
        for (int ct = 0; ct < 4; ++ct) {
            int gcol = (wc*4 + ct)*16 + lane;
            atomicAdd(&s_red[gcol*2],   ps[ct]);
            atomicAdd(&s_red[gcol*2+1], ps2[ct]);
        }
    }
    __syncthreads();
    if (threadIdx.x < 128) {
        atomicAdd(&gstats[threadIdx.x],       s_red[threadIdx.x*2]);
        atomicAdd(&gstats[128 + threadIdx.x], s_red[threadIdx.x*2+1]);
    }
}

// ---------------- K7: final BN + ReLU in place (float4) ----------------
__global__ void k7_final(float* __restrict__ Z, const float* __restrict__ gstats,
                         const float* __restrict__ gamma_p, const float* __restrict__ beta_p)
{
    __shared__ float s_sc[CDIM], s_sf[CDIM];
    if (threadIdx.x < CDIM) {
        int c = threadIdx.x;
        const float inv_n = 1.f / (float)NTOT;
        float mu  = gstats[c] * inv_n;
        float var = gstats[128 + c] * inv_n - mu*mu;
        float sc  = gamma_p[c] * rsqrtf(var + BNEPS);
        s_sc[c] = sc;
        s_sf[c] = beta_p[c] - mu*sc;
    }
    __syncthreads();
    int i4 = blockIdx.x * blockDim.x + threadIdx.x;
    if (i4 >= NTOT*32) return;
    float4 z = ((const float4*)Z)[i4];
    int c = (i4 & 31) * 4;
    z.x = fmaxf(fmaf(z.x, s_sc[c+0], s_sf[c+0]), 0.f);
    z.y = fmaxf(fmaf(z.y, s_sc[c+1], s_sf[c+1]), 0.f);
    z.z = fmaxf(fmaf(z.z, s_sc[c+2], s_sf[c+2]), 0.f);
    z.w = fmaxf(fmaf(z.w, s_sc[c+3], s_sf[c+3]), 0.f);
    ((float4*)Z)[i4] = z;
}

extern "C" void kernel_launch(void* const* d_in, const int* in_sizes, int n_in,
                              void* d_out, int out_size, void* d_ws, size_t ws_size,
                              hipStream_t stream)
{
    (void)in_sizes; (void)n_in; (void)out_size; (void)ws_size;
    const float* h_f  = (const float*)d_in[0];
    const float* x_f  = (const float*)d_in[1];
    const float* x_c  = (const float*)d_in[2];
    const float* h_c  = (const float*)d_in[3];
    const float* Wv   = (const float*)d_in[6];
    const float* Wo   = (const float*)d_in[7];
    const float* bo   = (const float*)d_in[8];
    const float* ga   = (const float*)d_in[9];
    const float* ba   = (const float*)d_in[10];
    const float* Wp   = (const float*)d_in[11];
    const float* bp   = (const float*)d_in[12];
    const float* gp   = (const float*)d_in[13];
    const float* betp = (const float*)d_in[14];

    char*  ws     = (char*)d_ws;
    unsigned short* Th  = (unsigned short*)ws;             // 32768 B (W1T)
    unsigned short* Thp = (unsigned short*)(ws + 32768);   // 32768 B (WpT)
    float* cstats = (float*)(ws + 65536);                  // 19456 B
    float* gstats = (float*)(ws + 65536 + 19456);          // 1024 B
    int*   tidx   = (int*)(ws + 65536 + 20480);            // 1,000,000 B
    unsigned short* A = (unsigned short*)(ws + 65536 + 20480 + 1000000); // 12.8 MB (bf16)
    float* Z      = (float*)d_out;

    hipMemsetAsync(ws + 65536, 0, 20480, stream);          // zero cstats + gstats

    k1_w1    <<<dim3(CDIM),        dim3(CDIM), 0, stream>>>(Wv, Wo, Th);
    k1b_wp   <<<dim3(CDIM),        dim3(CDIM), 0, stream>>>(Wp, Thp);
    k2_topk  <<<dim3(43, NCHUNKS), dim3(512),  0, stream>>>(x_c, h_c, tidx);
    k3_gemm1 <<<dim3(43, NCHUNKS), dim3(512),  0, stream>>>(x_f, h_f, tidx, Th, bo, A, cstats);
    k5_gemm2 <<<dim3(43, NCHUNKS), dim3(512),  0, stream>>>(A, Thp, bp, ga, ba, cstats, Z, gstats);
    k7_final <<<dim3((NTOT*32 + 255)/256), dim3(256), 0, stream>>>(Z, gstats, gp, betp);
}

// Round 25
// 149.401 us; speedup vs baseline: 2.0949x; 2.0949x over previous
//
#include <hip/hip_runtime.h>
#include <hip/hip_bf16.h>
#include <math.h>

#define NTOT    50000
#define CDIM    128
#define FCHUNK  2714
#define MCH     18
#define NREM    (NTOT - MCH*FCHUNK)   /* 1148 */
#define NCHUNKS 19
#define TOPKN   5
#define INNERD  512
#define BNEPS   1e-5f
#define SEGS    64
#define RPT     8     /* rows per thread (512-thread k2, 64 segs) */
#define CAP     25
#define APAD    136   /* ushort stride, 272B = 17*16 -> b128-aligned rows */
#define WPAD    40    /* ushort stride, 80B = 5*16  -> b128-aligned rows */

typedef __attribute__((ext_vector_type(8))) short short8v;   // 8 bf16 = 4 VGPR
typedef __attribute__((ext_vector_type(4))) float float4v;   // MFMA acc

static __device__ __forceinline__ int chunk_n(int chunk) {
    return (chunk < MCH) ? FCHUNK : NREM;
}

static __device__ __forceinline__ unsigned short bf16hi(float v) {
    return (unsigned short)(__float_as_uint(v) >> 16);   // truncation
}

static __device__ __forceinline__ float bf16tof(unsigned short u) {
    return __uint_as_float((unsigned)u << 16);
}

// strict-> sorted insert == lax.top_k stable tie-break (ascending-j stream)
#define INS5(s, jj, V0,V1,V2,V3,V4,I0,I1,I2,I3,I4) \
    if (s > V4) { \
        if (s > V0)      { V4=V3;I4=I3; V3=V2;I3=I2; V2=V1;I2=I1; V1=V0;I1=I0; V0=s;I0=jj; } \
        else if (s > V1) { V4=V3;I4=I3; V3=V2;I3=I2; V2=V1;I2=I1; V1=s;I1=jj; } \
        else if (s > V2) { V4=V3;I4=I3; V3=V2;I3=I2; V2=s;I2=jj; } \
        else if (s > V3) { V4=V3;I4=I3; V3=s;I3=jj; } \
        else             { V4=s;I4=jj; } \
    }

// composite (val desc, idx asc) insert — order-independent == stable top-k
#define INS5C(s, jj, V0,V1,V2,V3,V4,I0,I1,I2,I3,I4) \
    if ((s > V4) || (s == V4 && jj < I4)) { \
        if ((s > V0) || (s == V0 && jj < I0))      { V4=V3;I4=I3; V3=V2;I3=I2; V2=V1;I2=I1; V1=V0;I1=I0; V0=s;I0=jj; } \
        else if ((s > V1) || (s == V1 && jj < I1)) { V4=V3;I4=I3; V3=V2;I3=I2; V2=V1;I2=I1; V1=s;I1=jj; } \
        else if ((s > V2) || (s == V2 && jj < I2)) { V4=V3;I4=I3; V3=V2;I3=I2; V2=s;I2=jj; } \
        else if ((s > V3) || (s == V3 && jj < I3)) { V4=V3;I4=I3; V3=s;I3=jj; } \
        else                                        { V4=s;I4=jj; } \
    }

#define CAS(x, y) { float lo_ = fminf(x, y), hi_ = fmaxf(x, y); x = lo_; y = hi_; }

// ---- K1: W1 = Wv @ Wo, emit W1^T as bf16 (truncated) [col][k] ----
__global__ void k1_w1(const float* __restrict__ Wv, const float* __restrict__ Wo,
                      unsigned short* __restrict__ Th)
{
    __shared__ float s_wv[INNERD];
    int r = blockIdx.x;
    for (int t = threadIdx.x; t < INNERD; t += blockDim.x) s_wv[t] = Wv[r*INNERD + t];
    __syncthreads();
    int c = threadIdx.x;
    float acc = 0.f;
    #pragma unroll 8
    for (int k = 0; k < INNERD; ++k) acc = fmaf(s_wv[k], Wo[k*CDIM + c], acc);
    Th[c*CDIM + r] = bf16hi(acc);    // transposed: [col][k]
}

// ---- K1b: Wp^T -> bf16 (own buffer; launched up front) ----
__global__ void k1b_wp(const float* __restrict__ Wp, unsigned short* __restrict__ Thp)
{
    int r = blockIdx.x, c = threadIdx.x;
    Thp[c*CDIM + r] = bf16hi(Wp[r*CDIM + c]);
}

// --- K2: top-5, 512 threads; 64 residue classes, 8 rows/thread (2x ILP) ---
__global__ __launch_bounds__(512) void k2_topk(const float* __restrict__ x_c,
                                               const float* __restrict__ h_c,
                                               int* __restrict__ tidx)
{
    __shared__ float2 s_x01[FCHUNK];
    __shared__ float  s_x2[FCHUNK];
    __shared__ float  scratch[4224];          // A: segmax[64][65]+thr | B: cnt/cv/cj
    int chunk = blockIdx.y;
    int base  = chunk * FCHUNK;
    int n     = chunk_n(chunk);
    int row0  = blockIdx.x * 64;
    if (row0 >= n) return;

    for (int e = threadIdx.x; e < n; e += 512) {
        s_x01[e] = make_float2(x_c[(base+e)*3], x_c[(base+e)*3 + 1]);
        s_x2[e]  = x_c[(base+e)*3 + 2];
    }
    __syncthreads();

    int seg = threadIdx.x & 63;               // residue class: j = seg + 64t
    int g   = threadIdx.x >> 6;               // 0..7; rows g, g+8, ..., g+56

    float h0[RPT], h1[RPT], h2[RPT];
    #pragma unroll
    for (int r = 0; r < RPT; ++r) {
        int row = row0 + g + 8*r;
        bool v = row < n;
        h0[r] = v ? h_c[(base+row)*3  ] : 0.f;
        h1[r] = v ? h_c[(base+row)*3+1] : 0.f;
        h2[r] = v ? h_c[(base+row)*3+2] : 0.f;
    }

    // ---- pass 1: branchless residue-class maxes, 8 rows per x-read ----
    float m[RPT];
    #pragma unroll
    for (int r = 0; r < RPT; ++r) m[r] = -INFINITY;
    #pragma unroll 2
    for (int j = seg; j < n; j += SEGS) {
        float2 x01 = s_x01[j];
        float  xz  = s_x2[j];
        #pragma unroll
        for (int r = 0; r < RPT; ++r)
            m[r] = fmaxf(m[r], fmaf(xz,h2[r], fmaf(x01.y,h1[r], x01.x*h0[r])));
    }
    float* s_segmax = scratch;                // [64][65]
    float* s_thr    = scratch + 64*65;        // [64]
    #pragma unroll
    for (int r = 0; r < RPT; ++r) s_segmax[(g+8*r)*65 + seg] = m[r];
    __syncthreads();

    // ---- threshold: 5th largest of 8 supersegments-of-8 (T <= v5) ----
    if (threadIdx.x < 64) {
        int lr = threadIdx.x;
        const float* sm = &s_segmax[lr*65];
        float b[8];
        #pragma unroll
        for (int ss = 0; ss < 8; ++ss) {
            float m0 = fmaxf(fmaxf(sm[ss*8+0],sm[ss*8+1]), fmaxf(sm[ss*8+2],sm[ss*8+3]));
            float m1 = fmaxf(fmaxf(sm[ss*8+4],sm[ss*8+5]), fmaxf(sm[ss*8+6],sm[ss*8+7]));
            b[ss] = fmaxf(m0, m1);
        }
        float b0=b[0],b1=b[1],b2=b[2],b3=b[3],b4=b[4],b5=b[5],b6=b[6],b7=b[7];
        CAS(b0,b1); CAS(b2,b3); CAS(b4,b5); CAS(b6,b7);
        CAS(b0,b2); CAS(b1,b3); CAS(b4,b6); CAS(b5,b7);
        CAS(b1,b2); CAS(b5,b6);
        CAS(b0,b4); CAS(b1,b5); CAS(b2,b6); CAS(b3,b7);
        CAS(b2,b4); CAS(b3,b5);
        CAS(b1,b2); CAS(b3,b4); CAS(b5,b6);
        s_thr[lr] = (row0 + lr < n) ? b3 : INFINITY;   // ascending[3] = 5th largest
    }
    __syncthreads();
    float thr[RPT];
    #pragma unroll
    for (int r = 0; r < RPT; ++r) thr[r] = s_thr[g + 8*r];
    __syncthreads();

    int*   s_cnt = (int*)scratch;             // [64]
    float* s_cv  = scratch + 64;              // [64][CAP]
    int*   s_cj  = (int*)(scratch + 64 + 64*CAP); // [64][CAP]
    if (threadIdx.x < 64) s_cnt[threadIdx.x] = 0;
    __syncthreads();

    // ---- pass 2: append candidates >= thr (identical fma order -> exact bits) ----
    #pragma unroll 2
    for (int j = seg; j < n; j += SEGS) {
        float2 x01 = s_x01[j];
        float  xz  = s_x2[j];
        #pragma unroll
        for (int r = 0; r < RPT; ++r) {
            float d = fmaf(xz,h2[r], fmaf(x01.y,h1[r], x01.x*h0[r]));
            if (!(d < thr[r])) {
                int lr = g + 8*r;
                int p = atomicAdd(&s_cnt[lr], 1);
                if (p < CAP) { s_cv[lr*CAP+p] = d; s_cj[lr*CAP+p] = j; }
            }
        }
    }
    __syncthreads();

    // ---- merge: composite top-5 over ~7 candidates per row ----
    if (threadIdx.x < 64) {
        int lr = threadIdx.x, row = row0 + lr;
        if (row < n) {
            float v0=-INFINITY,v1=-INFINITY,v2=-INFINITY,v3=-INFINITY,v4=-INFINITY;
            int i0=0x7fffffff,i1=0x7fffffff,i2=0x7fffffff,i3=0x7fffffff,i4=0x7fffffff;
            int mcnt = s_cnt[lr];
            if (mcnt <= CAP) {
                for (int t = 0; t < mcnt; ++t) {
                    float s = s_cv[lr*CAP + t]; int jj = s_cj[lr*CAP + t];
                    INS5C(s, jj, v0,v1,v2,v3,v4, i0,i1,i2,i3,i4);
                }
            } else {
                // overflow fallback (P ~ 2e-6/row): serial ascending-j rescan
                float ha = h_c[(base+row)*3], hb = h_c[(base+row)*3+1], hc2 = h_c[(base+row)*3+2];
                v0=v1=v2=v3=v4=-INFINITY; i0=i1=i2=i3=i4=0;
                for (int jj = 0; jj < n; ++jj) {
                    float s = fmaf(s_x2[jj],hc2, fmaf(s_x01[jj].y,hb, s_x01[jj].x*ha));
                    INS5(s, jj, v0,v1,v2,v3,v4, i0,i1,i2,i3,i4);
                }
            }
            int o = (base+row)*TOPKN;
            tidx[o+0]=i0; tidx[o+1]=i1; tidx[o+2]=i2; tidx[o+3]=i3; tidx[o+4]=i4;
        }
    }
}

// ---- K3: gather + hsum -> bf16 MFMA GEMM; 512 thr, col-split waves; A out bf16 ----
__global__ __launch_bounds__(512) void k3_gemm1(const float* __restrict__ x_f,
                         const float* __restrict__ h_f,
                         const int* __restrict__ tidx,
                         const unsigned short* __restrict__ Th,
                         const float* __restrict__ bo, unsigned short* __restrict__ A,
                         float* __restrict__ cstats)
{
    __shared__ unsigned short s_ah[64][APAD];
    __shared__ unsigned short s_wh[128][WPAD];
    __shared__ int s_nb[64][TOPKN];
    __shared__ float s_red[256];
    int chunk = blockIdx.y;
    int base  = chunk * FCHUNK;
    int n     = chunk_n(chunk);
    int row0  = blockIdx.x * 64;
    if (row0 >= n) return;

    if (threadIdx.x < 64*TOPKN) {
        int e = threadIdx.x;
        int r = e / TOPKN, k = e % TOPKN;
        int il = row0 + r;
        int nb = 0;
        if (il < n) {
            int p = il*TOPKN + k;             // faithful tidx.T flatten order
            int q, m;
            if (n == FCHUNK) { q = p / FCHUNK; m = p - q*FCHUNK; }
            else             { q = p / NREM;   m = p - q*NREM; }
            nb = tidx[(base + m)*TOPKN + q];
        }
        s_nb[r][k] = nb;
    }
    __syncthreads();

    // gather + hsum (fp32), truncate to bf16 hi plane
    for (int e = threadIdx.x; e < 64*32; e += 512) {
        int r = e >> 5, c4 = e & 31;
        float4 acc4 = make_float4(0.f,0.f,0.f,0.f);
        int gr = row0 + r;
        if (gr < n) {
            acc4 = *(const float4*)&x_f[(base+gr)*CDIM + c4*4];
            #pragma unroll
            for (int k = 0; k < TOPKN; ++k) {
                float4 h4 = *(const float4*)&h_f[(base + s_nb[r][k])*CDIM + c4*4];
                acc4.x += h4.x; acc4.y += h4.y; acc4.z += h4.z; acc4.w += h4.w;
            }
        }
        uint2 ph;
        ph.x = (unsigned)bf16hi(acc4.x) | ((unsigned)bf16hi(acc4.y) << 16);
        ph.y = (unsigned)bf16hi(acc4.z) | ((unsigned)bf16hi(acc4.w) << 16);
        *(uint2*)&s_ah[r][c4*4] = ph;
    }

    int lane = threadIdx.x & 63;
    int w    = threadIdx.x >> 6;          // wave id 0..7
    int wr   = w & 3;                     // row block (16 rows)
    int wc   = w >> 2;                    // col half (64 cols)
    int lr   = lane & 15, lg = lane >> 4;
    float4v acc[4];
    #pragma unroll
    for (int ct = 0; ct < 4; ++ct) acc[ct] = (float4v){0.f,0.f,0.f,0.f};

    for (int ks = 0; ks < 4; ++ks) {
        __syncthreads();
        {   // stage W-hi tile: 4096 ushorts / 512 thr = 1 uint4 each
            int col = threadIdx.x >> 2, q = threadIdx.x & 3;
            *(uint4*)&s_wh[col][q*8] = *(const uint4*)&Th[col*CDIM + ks*32 + q*8];
        }
        __syncthreads();
        short8v a_h = *(const short8v*)&s_ah[wr*16 + lr][ks*32 + lg*8];
        #pragma unroll
        for (int ct = 0; ct < 4; ++ct) {
            short8v b_h = *(const short8v*)&s_wh[(wc*4 + ct)*16 + lr][lg*8];
            acc[ct] = __builtin_amdgcn_mfma_f32_16x16x32_bf16(a_h, b_h, acc[ct], 0,0,0);
        }
    }

    // epilogue + fused per-chunk stats. C/D: col=lane&15, row=(lane>>4)*4+reg
    float ps[4], ps2[4];
    #pragma unroll
    for (int ct = 0; ct < 4; ++ct) { ps[ct] = 0.f; ps2[ct] = 0.f; }
    #pragma unroll
    for (int ct = 0; ct < 4; ++ct) {
        int gcol = (wc*4 + ct)*16 + lr;
        float b = bo[gcol];
        #pragma unroll
        for (int ri = 0; ri < 4; ++ri) {
            int grow = row0 + wr*16 + lg*4 + ri;
            if (grow < n) {
                float v = acc[ct][ri] + b;
                A[(base+grow)*CDIM + gcol] = bf16hi(v);
                ps[ct] += v; ps2[ct] = fmaf(v, v, ps2[ct]);
            }
        }
    }
    #pragma unroll
    for (int ct = 0; ct < 4; ++ct) {          // reduce over lg within wave
        ps[ct]  += __shfl_xor(ps[ct], 16, 64);  ps[ct]  += __shfl_xor(ps[ct], 32, 64);
        ps2[ct] += __shfl_xor(ps2[ct], 16, 64); ps2[ct] += __shfl_xor(ps2[ct], 32, 64);
    }
    __syncthreads();
    if (threadIdx.x < 256) s_red[threadIdx.x] = 0.f;
    __syncthreads();
    if (lane < 16) {
        #pragma unroll
        for (int ct = 0; ct < 4; ++ct) {
            int gcol = (wc*4 + ct)*16 + lane;
            atomicAdd(&s_red[gcol*2],   ps[ct]);
            atomicAdd(&s_red[gcol*2+1], ps2[ct]);
        }
    }
    __syncthreads();
    if (threadIdx.x < 128) {
        atomicAdd(&cstats[chunk*256 + threadIdx.x],       s_red[threadIdx.x*2]);
        atomicAdd(&cstats[chunk*256 + 128 + threadIdx.x], s_red[threadIdx.x*2+1]);
    }
}

// ---- K5: relu(BN_chunk(A_bf16)) -> bf16 MFMA GEMM; 512 thr; fused gstats ----
__global__ __launch_bounds__(512) void k5_gemm2(const unsigned short* __restrict__ A,
                         const unsigned short* __restrict__ Thp,
                         const float* __restrict__ bp, const float* __restrict__ gamma_a,
                         const float* __restrict__ beta_a, const float* __restrict__ cstats,
                         float* __restrict__ Z, float* __restrict__ gstats)
{
    __shared__ unsigned short s_ah[64][APAD];
    __shared__ unsigned short s_wh[128][WPAD];
    __shared__ float s_sc[CDIM], s_sf[CDIM];
    __shared__ float s_red[256];
    int chunk = blockIdx.y;
    int base  = chunk * FCHUNK;
    int n     = chunk_n(chunk);
    int row0  = blockIdx.x * 64;
    if (row0 >= n) return;

    if (threadIdx.x < CDIM) {
        int c = threadIdx.x;
        float inv_n = 1.f / (float)n;
        float mu  = cstats[chunk*256 + c] * inv_n;
        float var = cstats[chunk*256 + 128 + c] * inv_n - mu*mu;
        float sc  = gamma_a[c] * rsqrtf(var + BNEPS);
        s_sc[c] = sc;
        s_sf[c] = beta_a[c] - mu*sc;
    }
    __syncthreads();

    for (int e = threadIdx.x; e < 64*32; e += 512) {
        int r = e >> 5, c4 = e & 31;
        uint2 ph = make_uint2(0u, 0u);
        int gr = row0 + r;
        if (gr < n) {
            uint2 a2 = *(const uint2*)&A[(base+gr)*CDIM + c4*4];
            int c = c4*4;
            float a0 = bf16tof((unsigned short)(a2.x & 0xFFFF));
            float a1 = bf16tof((unsigned short)(a2.x >> 16));
            float a2f = bf16tof((unsigned short)(a2.y & 0xFFFF));
            float a3 = bf16tof((unsigned short)(a2.y >> 16));
            float y0 = fmaxf(fmaf(a0, s_sc[c+0], s_sf[c+0]), 0.f);
            float y1 = fmaxf(fmaf(a1, s_sc[c+1], s_sf[c+1]), 0.f);
            float y2 = fmaxf(fmaf(a2f, s_sc[c+2], s_sf[c+2]), 0.f);
            float y3 = fmaxf(fmaf(a3, s_sc[c+3], s_sf[c+3]), 0.f);
            ph.x = (unsigned)bf16hi(y0) | ((unsigned)bf16hi(y1) << 16);
            ph.y = (unsigned)bf16hi(y2) | ((unsigned)bf16hi(y3) << 16);
        }
        *(uint2*)&s_ah[r][c4*4] = ph;
    }

    int lane = threadIdx.x & 63;
    int w    = threadIdx.x >> 6;
    int wr   = w & 3;
    int wc   = w >> 2;
    int lr   = lane & 15, lg = lane >> 4;
    float4v acc[4];
    #pragma unroll
    for (int ct = 0; ct < 4; ++ct) acc[ct] = (float4v){0.f,0.f,0.f,0.f};

    for (int ks = 0; ks < 4; ++ks) {
        __syncthreads();
        {
            int col = threadIdx.x >> 2, q = threadIdx.x & 3;
            *(uint4*)&s_wh[col][q*8] = *(const uint4*)&Thp[col*CDIM + ks*32 + q*8];
        }
        __syncthreads();
        short8v a_h = *(const short8v*)&s_ah[wr*16 + lr][ks*32 + lg*8];
        #pragma unroll
        for (int ct = 0; ct < 4; ++ct) {
            short8v b_h = *(const short8v*)&s_wh[(wc*4 + ct)*16 + lr][lg*8];
            acc[ct] = __builtin_amdgcn_mfma_f32_16x16x32_bf16(a_h, b_h, acc[ct], 0,0,0);
        }
    }

    float ps[4], ps2[4];
    #pragma unroll
    for (int ct = 0; ct < 4; ++ct) { ps[ct] = 0.f; ps2[ct] = 0.f; }
    #pragma unroll
    for (int ct = 0; ct < 4; ++ct) {
        int gcol = (wc*4 + ct)*16 + lr;
        float b = bp[gcol];
        #pragma unroll
        for (int ri = 0; ri < 4; ++ri) {
            int grow = row0 + wr*16 + lg*4 + ri;
            if (grow < n) {
                float v = acc[ct][ri] + b;
                Z[(base+grow)*CDIM + gcol] = v;
                ps[ct] += v; ps2[ct] = fmaf(v, v, ps2[ct]);
            }
        }
    }
    #pragma unroll
    for (int ct = 0; ct < 4; ++ct) {
        ps[ct]  += __shfl_xor(ps[ct], 16, 64);  ps[ct]  += __shfl_xor(ps[ct], 32, 64);
        ps2[ct] += __shfl_xor(ps2[ct], 16, 64); ps2[ct] += __shfl_xor(ps2[ct], 32, 64);
    }
    __syncthreads();
    if (threadIdx.x < 256) s_red[threadIdx.x] = 0.f;
    __syncthreads();
    if (lane < 16) {
        #pragma unroll
        for (int ct = 0; ct < 4; ++ct) {
            int gcol = (wc*4 + ct)*16 + lane;
            atomicAdd(&s_red[gcol*2],   ps[ct]);
            atomicAdd(&s_red[gcol*2+1], ps2[ct]);
        }
    }
    __syncthreads();
    if (threadIdx.x < 128) {
        atomicAdd(&gstats[threadIdx.x],       s_red[threadIdx.x*2]);
        atomicAdd(&gstats[128 + threadIdx.x], s_red[threadIdx.x*2+1]);
    }
}

// ---------------- K7: final BN + ReLU in place (float4) ----------------
__global__ void k7_final(float* __restrict__ Z, const float* __restrict__ gstats,
                         const float* __restrict__ gamma_p, const float* __restrict__ beta_p)
{
    __shared__ float s_sc[CDIM], s_sf[CDIM];
    if (threadIdx.x < CDIM) {
        int c = threadIdx.x;
        const float inv_n = 1.f / (float)NTOT;
        float mu  = gstats[c] * inv_n;
        float var = gstats[128 + c] * inv_n - mu*mu;
        float sc  = gamma_p[c] * rsqrtf(var + BNEPS);
        s_sc[c] = sc;
        s_sf[c] = beta_p[c] - mu*sc;
    }
    __syncthreads();
    int i4 = blockIdx.x * blockDim.x + threadIdx.x;
    if (i4 >= NTOT*32) return;
    float4 z = ((const float4*)Z)[i4];
    int c = (i4 & 31) * 4;
    z.x = fmaxf(fmaf(z.x, s_sc[c+0], s_sf[c+0]), 0.f);
    z.y = fmaxf(fmaf(z.y, s_sc[c+1], s_sf[c+1]), 0.f);
    z.z = fmaxf(fmaf(z.z, s_sc[c+2], s_sf[c+2]), 0.f);
    z.w = fmaxf(fmaf(z.w, s_sc[c+3], s_sf[c+3]), 0.f);
    ((float4*)Z)[i4] = z;
}

extern "C" void kernel_launch(void* const* d_in, const int* in_sizes, int n_in,
                              void* d_out, int out_size, void* d_ws, size_t ws_size,
                              hipStream_t stream)
{
    (void)in_sizes; (void)n_in; (void)out_size; (void)ws_size;
    const float* h_f  = (const float*)d_in[0];
    const float* x_f  = (const float*)d_in[1];
    const float* x_c  = (const float*)d_in[2];
    const float* h_c  = (const float*)d_in[3];
    const float* Wv   = (const float*)d_in[6];
    const float* Wo   = (const float*)d_in[7];
    const float* bo   = (const float*)d_in[8];
    const float* ga   = (const float*)d_in[9];
    const float* ba   = (const float*)d_in[10];
    const float* Wp   = (const float*)d_in[11];
    const float* bp   = (const float*)d_in[12];
    const float* gp   = (const float*)d_in[13];
    const float* betp = (const float*)d_in[14];

    char*  ws     = (char*)d_ws;
    unsigned short* Th  = (unsigned short*)ws;             // 32768 B (W1T)
    unsigned short* Thp = (unsigned short*)(ws + 32768);   // 32768 B (WpT)
    float* cstats = (float*)(ws + 65536);                  // 19456 B
    float* gstats = (float*)(ws + 65536 + 19456);          // 1024 B
    int*   tidx   = (int*)(ws + 65536 + 20480);            // 1,000,000 B
    unsigned short* A = (unsigned short*)(ws + 65536 + 20480 + 1000000); // 12.8 MB (bf16)
    float* Z      = (float*)d_out;

    hipMemsetAsync(ws + 65536, 0, 20480, stream);          // zero cstats + gstats

    k1_w1    <<<dim3(CDIM),        dim3(CDIM), 0, stream>>>(Wv, Wo, Th);
    k1b_wp   <<<dim3(CDIM),        dim3(CDIM), 0, stream>>>(Wp, Thp);
    k2_topk  <<<dim3(43, NCHUNKS), dim3(512),  0, stream>>>(x_c, h_c, tidx);
    k3_gemm1 <<<dim3(43, NCHUNKS), dim3(512),  0, stream>>>(x_f, h_f, tidx, Th, bo, A, cstats);
    k5_gemm2 <<<dim3(43, NCHUNKS), dim3(512),  0, stream>>>(A, Thp, bp, ga, ba, cstats, Z, gstats);
    k7_final <<<dim3((NTOT*32 + 255)/256), dim3(256), 0, stream>>>(Z, gstats, gp, betp);
}

// Round 26
// 140.934 us; speedup vs baseline: 2.2207x; 1.0601x over previous
//
#include <hip/hip_runtime.h>
#include <hip/hip_bf16.h>
#include <math.h>

#define NTOT    50000
#define CDIM    128
#define FCHUNK  2714
#define MCH     18
#define NREM    (NTOT - MCH*FCHUNK)   /* 1148 */
#define NCHUNKS 19
#define TOPKN   5
#define INNERD  512
#define BNEPS   1e-5f
#define SEGS    64
#define RPT     10    /* rows per thread (512-thread k2, 64 segs, 80-row tile) */
#define KROWS   80    /* rows per k2 block */
#define KBLK    34    /* ceil(2714/80) */
#define CAP     25
#define APAD    136   /* ushort stride, 272B = 17*16 -> b128-aligned rows */
#define WPAD    40    /* ushort stride, 80B = 5*16  -> b128-aligned rows */

typedef __attribute__((ext_vector_type(8))) short short8v;   // 8 bf16 = 4 VGPR
typedef __attribute__((ext_vector_type(4))) float float4v;   // MFMA acc

static __device__ __forceinline__ int chunk_n(int chunk) {
    return (chunk < MCH) ? FCHUNK : NREM;
}

static __device__ __forceinline__ unsigned short bf16hi(float v) {
    return (unsigned short)(__float_as_uint(v) >> 16);   // truncation
}

static __device__ __forceinline__ float bf16tof(unsigned short u) {
    return __uint_as_float((unsigned)u << 16);
}

// strict-> sorted insert == lax.top_k stable tie-break (ascending-j stream)
#define INS5(s, jj, V0,V1,V2,V3,V4,I0,I1,I2,I3,I4) \
    if (s > V4) { \
        if (s > V0)      { V4=V3;I4=I3; V3=V2;I3=I2; V2=V1;I2=I1; V1=V0;I1=I0; V0=s;I0=jj; } \
        else if (s > V1) { V4=V3;I4=I3; V3=V2;I3=I2; V2=V1;I2=I1; V1=s;I1=jj; } \
        else if (s > V2) { V4=V3;I4=I3; V3=V2;I3=I2; V2=s;I2=jj; } \
        else if (s > V3) { V4=V3;I4=I3; V3=s;I3=jj; } \
        else             { V4=s;I4=jj; } \
    }

// composite (val desc, idx asc) insert — order-independent == stable top-k
#define INS5C(s, jj, V0,V1,V2,V3,V4,I0,I1,I2,I3,I4) \
    if ((s > V4) || (s == V4 && jj < I4)) { \
        if ((s > V0) || (s == V0 && jj < I0))      { V4=V3;I4=I3; V3=V2;I3=I2; V2=V1;I2=I1; V1=V0;I1=I0; V0=s;I0=jj; } \
        else if ((s > V1) || (s == V1 && jj < I1)) { V4=V3;I4=I3; V3=V2;I3=I2; V2=V1;I2=I1; V1=s;I1=jj; } \
        else if ((s > V2) || (s == V2 && jj < I2)) { V4=V3;I4=I3; V3=V2;I3=I2; V2=s;I2=jj; } \
        else if ((s > V3) || (s == V3 && jj < I3)) { V4=V3;I4=I3; V3=s;I3=jj; } \
        else                                        { V4=s;I4=jj; } \
    }

#define CAS(x, y) { float lo_ = fminf(x, y), hi_ = fmaxf(x, y); x = lo_; y = hi_; }

// ---- K1: W1 = Wv @ Wo, emit W1^T as bf16 (truncated) [col][k] ----
__global__ void k1_w1(const float* __restrict__ Wv, const float* __restrict__ Wo,
                      unsigned short* __restrict__ Th)
{
    __shared__ float s_wv[INNERD];
    int r = blockIdx.x;
    for (int t = threadIdx.x; t < INNERD; t += blockDim.x) s_wv[t] = Wv[r*INNERD + t];
    __syncthreads();
    int c = threadIdx.x;
    float acc = 0.f;
    #pragma unroll 8
    for (int k = 0; k < INNERD; ++k) acc = fmaf(s_wv[k], Wo[k*CDIM + c], acc);
    Th[c*CDIM + r] = bf16hi(acc);    // transposed: [col][k]
}

// ---- K1b: Wp^T -> bf16 (own buffer; launched up front) ----
__global__ void k1b_wp(const float* __restrict__ Wp, unsigned short* __restrict__ Thp)
{
    int r = blockIdx.x, c = threadIdx.x;
    Thp[c*CDIM + r] = bf16hi(Wp[r*CDIM + c]);
}

// --- K2: top-5, 512 threads; 64 residue classes, 10 rows/thread, 80-row tile ---
__global__ __launch_bounds__(512) void k2_topk(const float* __restrict__ x_c,
                                               const float* __restrict__ h_c,
                                               int* __restrict__ tidx)
{
    __shared__ float2 s_x01[FCHUNK];
    __shared__ float  s_x2[FCHUNK];
    __shared__ float  scratch[5280];          // A: segmax[80][65]+thr[80] | B: cnt/cv/cj
    int chunk = blockIdx.y;
    int base  = chunk * FCHUNK;
    int n     = chunk_n(chunk);
    int row0  = blockIdx.x * KROWS;
    if (row0 >= n) return;

    for (int e = threadIdx.x; e < n; e += 512) {
        s_x01[e] = make_float2(x_c[(base+e)*3], x_c[(base+e)*3 + 1]);
        s_x2[e]  = x_c[(base+e)*3 + 2];
    }
    __syncthreads();

    int seg = threadIdx.x & 63;               // residue class: j = seg + 64t
    int g   = threadIdx.x >> 6;               // 0..7; rows g, g+8, ..., g+72

    float h0[RPT], h1[RPT], h2[RPT];
    #pragma unroll
    for (int r = 0; r < RPT; ++r) {
        int row = row0 + g + 8*r;
        bool v = row < n;
        h0[r] = v ? h_c[(base+row)*3  ] : 0.f;
        h1[r] = v ? h_c[(base+row)*3+1] : 0.f;
        h2[r] = v ? h_c[(base+row)*3+2] : 0.f;
    }

    // ---- pass 1: branchless residue-class maxes, 10 rows per x-read ----
    float m[RPT];
    #pragma unroll
    for (int r = 0; r < RPT; ++r) m[r] = -INFINITY;
    #pragma unroll 2
    for (int j = seg; j < n; j += SEGS) {
        float2 x01 = s_x01[j];
        float  xz  = s_x2[j];
        #pragma unroll
        for (int r = 0; r < RPT; ++r)
            m[r] = fmaxf(m[r], fmaf(xz,h2[r], fmaf(x01.y,h1[r], x01.x*h0[r])));
    }
    float* s_segmax = scratch;                // [80][65]
    float* s_thr    = scratch + KROWS*65;     // [80]
    #pragma unroll
    for (int r = 0; r < RPT; ++r) s_segmax[(g+8*r)*65 + seg] = m[r];
    __syncthreads();

    // ---- threshold: 5th largest of 8 supersegments-of-8 (T <= v5) ----
    if (threadIdx.x < KROWS) {
        int lr = threadIdx.x;
        const float* sm = &s_segmax[lr*65];
        float b[8];
        #pragma unroll
        for (int ss = 0; ss < 8; ++ss) {
            float m0 = fmaxf(fmaxf(sm[ss*8+0],sm[ss*8+1]), fmaxf(sm[ss*8+2],sm[ss*8+3]));
            float m1 = fmaxf(fmaxf(sm[ss*8+4],sm[ss*8+5]), fmaxf(sm[ss*8+6],sm[ss*8+7]));
            b[ss] = fmaxf(m0, m1);
        }
        float b0=b[0],b1=b[1],b2=b[2],b3=b[3],b4=b[4],b5=b[5],b6=b[6],b7=b[7];
        CAS(b0,b1); CAS(b2,b3); CAS(b4,b5); CAS(b6,b7);
        CAS(b0,b2); CAS(b1,b3); CAS(b4,b6); CAS(b5,b7);
        CAS(b1,b2); CAS(b5,b6);
        CAS(b0,b4); CAS(b1,b5); CAS(b2,b6); CAS(b3,b7);
        CAS(b2,b4); CAS(b3,b5);
        CAS(b1,b2); CAS(b3,b4); CAS(b5,b6);
        s_thr[lr] = (row0 + lr < n) ? b3 : INFINITY;   // ascending[3] = 5th largest
    }
    __syncthreads();
    float thr[RPT];
    #pragma unroll
    for (int r = 0; r < RPT; ++r) thr[r] = s_thr[g + 8*r];
    __syncthreads();

    int*   s_cnt = (int*)scratch;             // [80]
    float* s_cv  = scratch + KROWS;           // [80][CAP]
    int*   s_cj  = (int*)(scratch + KROWS + KROWS*CAP); // [80][CAP]
    if (threadIdx.x < KROWS) s_cnt[threadIdx.x] = 0;
    __syncthreads();

    // ---- pass 2: append candidates >= thr (identical fma order -> exact bits) ----
    #pragma unroll 2
    for (int j = seg; j < n; j += SEGS) {
        float2 x01 = s_x01[j];
        float  xz  = s_x2[j];
        #pragma unroll
        for (int r = 0; r < RPT; ++r) {
            float d = fmaf(xz,h2[r], fmaf(x01.y,h1[r], x01.x*h0[r]));
            if (!(d < thr[r])) {
                int lr = g + 8*r;
                int p = atomicAdd(&s_cnt[lr], 1);
                if (p < CAP) { s_cv[lr*CAP+p] = d; s_cj[lr*CAP+p] = j; }
            }
        }
    }
    __syncthreads();

    // ---- merge: composite top-5 over ~7 candidates per row ----
    if (threadIdx.x < KROWS) {
        int lr = threadIdx.x, row = row0 + lr;
        if (row < n) {
            float v0=-INFINITY,v1=-INFINITY,v2=-INFINITY,v3=-INFINITY,v4=-INFINITY;
            int i0=0x7fffffff,i1=0x7fffffff,i2=0x7fffffff,i3=0x7fffffff,i4=0x7fffffff;
            int mcnt = s_cnt[lr];
            if (mcnt <= CAP) {
                for (int t = 0; t < mcnt; ++t) {
                    float s = s_cv[lr*CAP + t]; int jj = s_cj[lr*CAP + t];
                    INS5C(s, jj, v0,v1,v2,v3,v4, i0,i1,i2,i3,i4);
                }
            } else {
                // overflow fallback (P ~ 2e-6/row): serial ascending-j rescan
                float ha = h_c[(base+row)*3], hb = h_c[(base+row)*3+1], hc2 = h_c[(base+row)*3+2];
                v0=v1=v2=v3=v4=-INFINITY; i0=i1=i2=i3=i4=0;
                for (int jj = 0; jj < n; ++jj) {
                    float s = fmaf(s_x2[jj],hc2, fmaf(s_x01[jj].y,hb, s_x01[jj].x*ha));
                    INS5(s, jj, v0,v1,v2,v3,v4, i0,i1,i2,i3,i4);
                }
            }
            int o = (base+row)*TOPKN;
            tidx[o+0]=i0; tidx[o+1]=i1; tidx[o+2]=i2; tidx[o+3]=i3; tidx[o+4]=i4;
        }
    }
}

// ---- K3: gather + hsum -> bf16 MFMA GEMM; 512 thr, col-split waves; A out bf16 ----
__global__ __launch_bounds__(512) void k3_gemm1(const float* __restrict__ x_f,
                         const float* __restrict__ h_f,
                         const int* __restrict__ tidx,
                         const unsigned short* __restrict__ Th,
                         const float* __restrict__ bo, unsigned short* __restrict__ A,
                         float* __restrict__ cstats)
{
    __shared__ unsigned short s_ah[64][APAD];
    __shared__ unsigned short s_wh[128][WPAD];
    __shared__ int s_nb[64][TOPKN];
    __shared__ float s_red[256];
    int chunk = blockIdx.y;
    int base  = chunk * FCHUNK;
    int n     = chunk_n(chunk);
    int row0  = blockIdx.x * 64;
    if (row0 >= n) return;

    if (threadIdx.x < 64*TOPKN) {
        int e = threadIdx.x;
        int r = e / TOPKN, k = e % TOPKN;
        int il = row0 + r;
        int nb = 0;
        if (il < n) {
            int p = il*TOPKN + k;             // faithful tidx.T flatten order
            int q, m;
            if (n == FCHUNK) { q = p / FCHUNK; m = p - q*FCHUNK; }
            else             { q = p / NREM;   m = p - q*NREM; }
            nb = tidx[(base + m)*TOPKN + q];
        }
        s_nb[r][k] = nb;
    }
    __syncthreads();

    // gather + hsum (fp32), truncate to bf16 hi plane
    for (int e = threadIdx.x; e < 64*32; e += 512) {
        int r = e >> 5, c4 = e & 31;
        float4 acc4 = make_float4(0.f,0.f,0.f,0.f);
        int gr = row0 + r;
        if (gr < n) {
            acc4 = *(const float4*)&x_f[(base+gr)*CDIM + c4*4];
            #pragma unroll
            for (int k = 0; k < TOPKN; ++k) {
                float4 h4 = *(const float4*)&h_f[(base + s_nb[r][k])*CDIM + c4*4];
                acc4.x += h4.x; acc4.y += h4.y; acc4.z += h4.z; acc4.w += h4.w;
            }
        }
        uint2 ph;
        ph.x = (unsigned)bf16hi(acc4.x) | ((unsigned)bf16hi(acc4.y) << 16);
        ph.y = (unsigned)bf16hi(acc4.z) | ((unsigned)bf16hi(acc4.w) << 16);
        *(uint2*)&s_ah[r][c4*4] = ph;
    }

    int lane = threadIdx.x & 63;
    int w    = threadIdx.x >> 6;          // wave id 0..7
    int wr   = w & 3;                     // row block (16 rows)
    int wc   = w >> 2;                    // col half (64 cols)
    int lr   = lane & 15, lg = lane >> 4;
    float4v acc[4];
    #pragma unroll
    for (int ct = 0; ct < 4; ++ct) acc[ct] = (float4v){0.f,0.f,0.f,0.f};

    for (int ks = 0; ks < 4; ++ks) {
        __syncthreads();
        {   // stage W-hi tile: 4096 ushorts / 512 thr = 1 uint4 each
            int col = threadIdx.x >> 2, q = threadIdx.x & 3;
            *(uint4*)&s_wh[col][q*8] = *(const uint4*)&Th[col*CDIM + ks*32 + q*8];
        }
        __syncthreads();
        short8v a_h = *(const short8v*)&s_ah[wr*16 + lr][ks*32 + lg*8];
        #pragma unroll
        for (int ct = 0; ct < 4; ++ct) {
            short8v b_h = *(const short8v*)&s_wh[(wc*4 + ct)*16 + lr][lg*8];
            acc[ct] = __builtin_amdgcn_mfma_f32_16x16x32_bf16(a_h, b_h, acc[ct], 0,0,0);
        }
    }

    // epilogue + fused per-chunk stats. C/D: col=lane&15, row=(lane>>4)*4+reg
    float ps[4], ps2[4];
    #pragma unroll
    for (int ct = 0; ct < 4; ++ct) { ps[ct] = 0.f; ps2[ct] = 0.f; }
    #pragma unroll
    for (int ct = 0; ct < 4; ++ct) {
        int gcol = (wc*4 + ct)*16 + lr;
        float b = bo[gcol];
        #pragma unroll
        for (int ri = 0; ri < 4; ++ri) {
            int grow = row0 + wr*16 + lg*4 + ri;
            if (grow < n) {
                float v = acc[ct][ri] + b;
                A[(base+grow)*CDIM + gcol] = bf16hi(v);
                ps[ct] += v; ps2[ct] = fmaf(v, v, ps2[ct]);
            }
        }
    }
    #pragma unroll
    for (int ct = 0; ct < 4; ++ct) {          // reduce over lg within wave
        ps[ct]  += __shfl_xor(ps[ct], 16, 64);  ps[ct]  += __shfl_xor(ps[ct], 32, 64);
        ps2[ct] += __shfl_xor(ps2[ct], 16, 64); ps2[ct] += __shfl_xor(ps2[ct], 32, 64);
    }
    __syncthreads();
    if (threadIdx.x < 256) s_red[threadIdx.x] = 0.f;
    __syncthreads();
    if (lane < 16) {
        #pragma unroll
        for (int ct = 0; ct < 4; ++ct) {
            int gcol = (wc*4 + ct)*16 + lane;
            atomicAdd(&s_red[gcol*2],   ps[ct]);
            atomicAdd(&s_red[gcol*2+1], ps2[ct]);
        }
    }
    __syncthreads();
    if (threadIdx.x < 128) {
        atomicAdd(&cstats[chunk*256 + threadIdx.x],       s_red[threadIdx.x*2]);
        atomicAdd(&cstats[chunk*256 + 128 + threadIdx.x], s_red[threadIdx.x*2+1]);
    }
}

// ---- K5: relu(BN_chunk(A_bf16)) -> bf16 MFMA GEMM; 512 thr; fused gstats ----
__global__ __launch_bounds__(512) void k5_gemm2(const unsigned short* __restrict__ A,
                         const unsigned short* __restrict__ Thp,
                         const float* __restrict__ bp, const float* __restrict__ gamma_a,
                         const float* __restrict__ beta_a, const float* __restrict__ cstats,
                         float* __restrict__ Z, float* __restrict__ gstats)
{
    __shared__ unsigned short s_ah[64][APAD];
    __shared__ unsigned short s_wh[128][WPAD];
    __shared__ float s_sc[CDIM], s_sf[CDIM];
    __shared__ float s_red[256];
    int chunk = blockIdx.y;
    int base  = chunk * FCHUNK;
    int n     = chunk_n(chunk);
    int row0  = blockIdx.x * 64;
    if (row0 >= n) return;

    if (threadIdx.x < CDIM) {
        int c = threadIdx.x;
        float inv_n = 1.f / (float)n;
        float mu  = cstats[chunk*256 + c] * inv_n;
        float var = cstats[chunk*256 + 128 + c] * inv_n - mu*mu;
        float sc  = gamma_a[c] * rsqrtf(var + BNEPS);
        s_sc[c] = sc;
        s_sf[c] = beta_a[c] - mu*sc;
    }
    __syncthreads();

    for (int e = threadIdx.x; e < 64*32; e += 512) {
        int r = e >> 5, c4 = e & 31;
        uint2 ph = make_uint2(0u, 0u);
        int gr = row0 + r;
        if (gr < n) {
            uint2 a2 = *(const uint2*)&A[(base+gr)*CDIM + c4*4];
            int c = c4*4;
            float a0 = bf16tof((unsigned short)(a2.x & 0xFFFF));
            float a1 = bf16tof((unsigned short)(a2.x >> 16));
            float a2f = bf16tof((unsigned short)(a2.y & 0xFFFF));
            float a3 = bf16tof((unsigned short)(a2.y >> 16));
            float y0 = fmaxf(fmaf(a0, s_sc[c+0], s_sf[c+0]), 0.f);
            float y1 = fmaxf(fmaf(a1, s_sc[c+1], s_sf[c+1]), 0.f);
            float y2 = fmaxf(fmaf(a2f, s_sc[c+2], s_sf[c+2]), 0.f);
            float y3 = fmaxf(fmaf(a3, s_sc[c+3], s_sf[c+3]), 0.f);
            ph.x = (unsigned)bf16hi(y0) | ((unsigned)bf16hi(y1) << 16);
            ph.y = (unsigned)bf16hi(y2) | ((unsigned)bf16hi(y3) << 16);
        }
        *(uint2*)&s_ah[r][c4*4] = ph;
    }

    int lane = threadIdx.x & 63;
    int w    = threadIdx.x >> 6;
    int wr   = w & 3;
    int wc   = w >> 2;
    int lr   = lane & 15, lg = lane >> 4;
    float4v acc[4];
    #pragma unroll
    for (int ct = 0; ct < 4; ++ct) acc[ct] = (float4v){0.f,0.f,0.f,0.f};

    for (int ks = 0; ks < 4; ++ks) {
        __syncthreads();
        {
            int col = threadIdx.x >> 2, q = threadIdx.x & 3;
            *(uint4*)&s_wh[col][q*8] = *(const uint4*)&Thp[col*CDIM + ks*32 + q*8];
        }
        __syncthreads();
        short8v a_h = *(const short8v*)&s_ah[wr*16 + lr][ks*32 + lg*8];
        #pragma unroll
        for (int ct = 0; ct < 4; ++ct) {
            short8v b_h = *(const short8v*)&s_wh[(wc*4 + ct)*16 + lr][lg*8];
            acc[ct] = __builtin_amdgcn_mfma_f32_16x16x32_bf16(a_h, b_h, acc[ct], 0,0,0);
        }
    }

    float ps[4], ps2[4];
    #pragma unroll
    for (int ct = 0; ct < 4; ++ct) { ps[ct] = 0.f; ps2[ct] = 0.f; }
    #pragma unroll
    for (int ct = 0; ct < 4; ++ct) {
        int gcol = (wc*4 + ct)*16 + lr;
        float b = bp[gcol];
        #pragma unroll
        for (int ri = 0; ri < 4; ++ri) {
            int grow = row0 + wr*16 + lg*4 + ri;
            if (grow < n) {
                float v = acc[ct][ri] + b;
                Z[(base+grow)*CDIM + gcol] = v;
                ps[ct] += v; ps2[ct] = fmaf(v, v, ps2[ct]);
            }
        }
    }
    #pragma unroll
    for (int ct = 0; ct < 4; ++ct) {
        ps[ct]  += __shfl_xor(ps[ct], 16, 64);  ps[ct]  += __shfl_xor(ps[ct], 32, 64);
        ps2[ct] += __shfl_xor(ps2[ct], 16, 64); ps2[ct] += __shfl_xor(ps2[ct], 32, 64);
    }
    __syncthreads();
    if (threadIdx.x < 256) s_red[threadIdx.x] = 0.f;
    __syncthreads();
    if (lane < 16) {
        #pragma unroll
        for (int ct = 0; ct < 4; ++ct) {
            int gcol = (wc*4 + ct)*16 + lane;
            atomicAdd(&s_red[gcol*2],   ps[ct]);
            atomicAdd(&s_red[gcol*2+1], ps2[ct]);
        }
    }
    __syncthreads();
    if (threadIdx.x < 128) {
        atomicAdd(&gstats[threadIdx.x],       s_red[threadIdx.x*2]);
        atomicAdd(&gstats[128 + threadIdx.x], s_red[threadIdx.x*2+1]);
    }
}

// ---------------- K7: final BN + ReLU in place (float4) ----------------
__global__ void k7_final(float* __restrict__ Z, const float* __restrict__ gstats,
                         const float* __restrict__ gamma_p, const float* __restrict__ beta_p)
{
    __shared__ float s_sc[CDIM], s_sf[CDIM];
    if (threadIdx.x < CDIM) {
        int c = threadIdx.x;
        const float inv_n = 1.f / (float)NTOT;
        float mu  = gstats[c] * inv_n;
        float var = gstats[128 + c] * inv_n - mu*mu;
        float sc  = gamma_p[c] * rsqrtf(var + BNEPS);
        s_sc[c] = sc;
        s_sf[c] = beta_p[c] - mu*sc;
    }
    __syncthreads();
    int i4 = blockIdx.x * blockDim.x + threadIdx.x;
    if (i4 >= NTOT*32) return;
    float4 z = ((const float4*)Z)[i4];
    int c = (i4 & 31) * 4;
    z.x = fmaxf(fmaf(z.x, s_sc[c+0], s_sf[c+0]), 0.f);
    z.y = fmaxf(fmaf(z.y, s_sc[c+1], s_sf[c+1]), 0.f);
    z.z = fmaxf(fmaf(z.z, s_sc[c+2], s_sf[c+2]), 0.f);
    z.w = fmaxf(fmaf(z.w, s_sc[c+3], s_sf[c+3]), 0.f);
    ((float4*)Z)[i4] = z;
}

extern "C" void kernel_launch(void* const* d_in, const int* in_sizes, int n_in,
                              void* d_out, int out_size, void* d_ws, size_t ws_size,
                              hipStream_t stream)
{
    (void)in_sizes; (void)n_in; (void)out_size; (void)ws_size;
    const float* h_f  = (const float*)d_in[0];
    const float* x_f  = (const float*)d_in[1];
    const float* x_c  = (const float*)d_in[2];
    const float* h_c  = (const float*)d_in[3];
    const float* Wv   = (const float*)d_in[6];
    const float* Wo   = (const float*)d_in[7];
    const float* bo   = (const float*)d_in[8];
    const float* ga   = (const float*)d_in[9];
    const float* ba   = (const float*)d_in[10];
    const float* Wp   = (const float*)d_in[11];
    const float* bp   = (const float*)d_in[12];
    const float* gp   = (const float*)d_in[13];
    const float* betp = (const float*)d_in[14];

    char*  ws     = (char*)d_ws;
    unsigned short* Th  = (unsigned short*)ws;             // 32768 B (W1T)
    unsigned short* Thp = (unsigned short*)(ws + 32768);   // 32768 B (WpT)
    float* cstats = (float*)(ws + 65536);                  // 19456 B
    float* gstats = (float*)(ws + 65536 + 19456);          // 1024 B
    int*   tidx   = (int*)(ws + 65536 + 20480);            // 1,000,000 B
    unsigned short* A = (unsigned short*)(ws + 65536 + 20480 + 1000000); // 12.8 MB (bf16)
    float* Z      = (float*)d_out;

    hipMemsetAsync(ws + 65536, 0, 20480, stream);          // zero cstats + gstats

    k1_w1    <<<dim3(CDIM),        dim3(CDIM), 0, stream>>>(Wv, Wo, Th);
    k1b_wp   <<<dim3(CDIM),        dim3(CDIM), 0, stream>>>(Wp, Thp);
    k2_topk  <<<dim3(KBLK, NCHUNKS), dim3(512), 0, stream>>>(x_c, h_c, tidx);
    k3_gemm1 <<<dim3(43, NCHUNKS), dim3(512),  0, stream>>>(x_f, h_f, tidx, Th, bo, A, cstats);
    k5_gemm2 <<<dim3(43, NCHUNKS), dim3(512),  0, stream>>>(A, Thp, bp, ga, ba, cstats, Z, gstats);
    k7_final <<<dim3((NTOT*32 + 255)/256), dim3(256), 0, stream>>>(Z, gstats, gp, betp);
}

// Round 27
// 135.651 us; speedup vs baseline: 2.3072x; 1.0389x over previous
//
#include <hip/hip_runtime.h>
#include <hip/hip_bf16.h>
#include <math.h>

#define NTOT    50000
#define CDIM    128
#define FCHUNK  2714
#define MCH     18
#define NREM    (NTOT - MCH*FCHUNK)   /* 1148 */
#define NCHUNKS 19
#define TOPKN   5
#define INNERD  512
#define BNEPS   1e-5f
#define SEGS    64
#define RPT     9     /* rows per thread (512-thread k2, 64 segs, 72-row tile) */
#define KROWS   72    /* rows per k2 block */
#define KBLK    38    /* ceil(2714/72) */
#define CAP     25
#define APAD    136   /* ushort stride, 272B = 17*16 -> b128-aligned rows */
#define WPAD    40    /* ushort stride, 80B = 5*16  -> b128-aligned rows */

typedef __attribute__((ext_vector_type(8))) short short8v;   // 8 bf16 = 4 VGPR
typedef __attribute__((ext_vector_type(4))) float float4v;   // MFMA acc

static __device__ __forceinline__ int chunk_n(int chunk) {
    return (chunk < MCH) ? FCHUNK : NREM;
}

static __device__ __forceinline__ unsigned short bf16hi(float v) {
    return (unsigned short)(__float_as_uint(v) >> 16);   // truncation
}

static __device__ __forceinline__ float bf16tof(unsigned short u) {
    return __uint_as_float((unsigned)u << 16);
}

// strict-> sorted insert == lax.top_k stable tie-break (ascending-j stream)
#define INS5(s, jj, V0,V1,V2,V3,V4,I0,I1,I2,I3,I4) \
    if (s > V4) { \
        if (s > V0)      { V4=V3;I4=I3; V3=V2;I3=I2; V2=V1;I2=I1; V1=V0;I1=I0; V0=s;I0=jj; } \
        else if (s > V1) { V4=V3;I4=I3; V3=V2;I3=I2; V2=V1;I2=I1; V1=s;I1=jj; } \
        else if (s > V2) { V4=V3;I4=I3; V3=V2;I3=I2; V2=s;I2=jj; } \
        else if (s > V3) { V4=V3;I4=I3; V3=s;I3=jj; } \
        else             { V4=s;I4=jj; } \
    }

// composite (val desc, idx asc) insert — order-independent == stable top-k
#define INS5C(s, jj, V0,V1,V2,V3,V4,I0,I1,I2,I3,I4) \
    if ((s > V4) || (s == V4 && jj < I4)) { \
        if ((s > V0) || (s == V0 && jj < I0))      { V4=V3;I4=I3; V3=V2;I3=I2; V2=V1;I2=I1; V1=V0;I1=I0; V0=s;I0=jj; } \
        else if ((s > V1) || (s == V1 && jj < I1)) { V4=V3;I4=I3; V3=V2;I3=I2; V2=V1;I2=I1; V1=s;I1=jj; } \
        else if ((s > V2) || (s == V2 && jj < I2)) { V4=V3;I4=I3; V3=V2;I3=I2; V2=s;I2=jj; } \
        else if ((s > V3) || (s == V3 && jj < I3)) { V4=V3;I4=I3; V3=s;I3=jj; } \
        else                                        { V4=s;I4=jj; } \
    }

#define CAS(x, y) { float lo_ = fminf(x, y), hi_ = fmaxf(x, y); x = lo_; y = hi_; }

// ---- K1: blocks 0..127: W1=Wv@Wo row -> Th; blocks 128..255: Wp row -> Thp ----
__global__ void k1_both(const float* __restrict__ Wv, const float* __restrict__ Wo,
                        const float* __restrict__ Wp,
                        unsigned short* __restrict__ Th, unsigned short* __restrict__ Thp)
{
    __shared__ float s_wv[INNERD];
    if (blockIdx.x < CDIM) {
        int r = blockIdx.x;
        for (int t = threadIdx.x; t < INNERD; t += blockDim.x) s_wv[t] = Wv[r*INNERD + t];
        __syncthreads();
        int c = threadIdx.x;
        float acc = 0.f;
        #pragma unroll 8
        for (int k = 0; k < INNERD; ++k) acc = fmaf(s_wv[k], Wo[k*CDIM + c], acc);
        Th[c*CDIM + r] = bf16hi(acc);    // transposed: [col][k]
    } else {
        int r = blockIdx.x - CDIM, c = threadIdx.x;
        Thp[c*CDIM + r] = bf16hi(Wp[r*CDIM + c]);
    }
}

// --- K2: top-5, 512 threads; 64 residue classes, 9 rows/thread, 72-row tile ---
__global__ __launch_bounds__(512) void k2_topk(const float* __restrict__ x_c,
                                               const float* __restrict__ h_c,
                                               int* __restrict__ tidx)
{
    __shared__ float2 s_x01[FCHUNK];
    __shared__ float  s_x2[FCHUNK];
    __shared__ float  scratch[4752];          // A: segmax[72][65]+thr[72] | B: cnt/cv/cj
    int chunk = blockIdx.y;
    int base  = chunk * FCHUNK;
    int n     = chunk_n(chunk);
    int row0  = blockIdx.x * KROWS;
    if (row0 >= n) return;

    for (int e = threadIdx.x; e < n; e += 512) {
        s_x01[e] = make_float2(x_c[(base+e)*3], x_c[(base+e)*3 + 1]);
        s_x2[e]  = x_c[(base+e)*3 + 2];
    }
    __syncthreads();

    int seg = threadIdx.x & 63;               // residue class: j = seg + 64t
    int g   = threadIdx.x >> 6;               // 0..7; rows g, g+8, ..., g+64

    float h0[RPT], h1[RPT], h2[RPT];
    #pragma unroll
    for (int r = 0; r < RPT; ++r) {
        int row = row0 + g + 8*r;
        bool v = row < n;
        h0[r] = v ? h_c[(base+row)*3  ] : 0.f;
        h1[r] = v ? h_c[(base+row)*3+1] : 0.f;
        h2[r] = v ? h_c[(base+row)*3+2] : 0.f;
    }

    // ---- pass 1: branchless residue-class maxes, 9 rows per x-read ----
    float m[RPT];
    #pragma unroll
    for (int r = 0; r < RPT; ++r) m[r] = -INFINITY;
    #pragma unroll 2
    for (int j = seg; j < n; j += SEGS) {
        float2 x01 = s_x01[j];
        float  xz  = s_x2[j];
        #pragma unroll
        for (int r = 0; r < RPT; ++r)
            m[r] = fmaxf(m[r], fmaf(xz,h2[r], fmaf(x01.y,h1[r], x01.x*h0[r])));
    }
    float* s_segmax = scratch;                // [72][65]
    float* s_thr    = scratch + KROWS*65;     // [72]
    #pragma unroll
    for (int r = 0; r < RPT; ++r) s_segmax[(g+8*r)*65 + seg] = m[r];
    __syncthreads();

    // ---- threshold: 5th largest of 8 supersegments-of-8 (T <= v5) ----
    if (threadIdx.x < KROWS) {
        int lr = threadIdx.x;
        const float* sm = &s_segmax[lr*65];
        float b[8];
        #pragma unroll
        for (int ss = 0; ss < 8; ++ss) {
            float m0 = fmaxf(fmaxf(sm[ss*8+0],sm[ss*8+1]), fmaxf(sm[ss*8+2],sm[ss*8+3]));
            float m1 = fmaxf(fmaxf(sm[ss*8+4],sm[ss*8+5]), fmaxf(sm[ss*8+6],sm[ss*8+7]));
            b[ss] = fmaxf(m0, m1);
        }
        float b0=b[0],b1=b[1],b2=b[2],b3=b[3],b4=b[4],b5=b[5],b6=b[6],b7=b[7];
        CAS(b0,b1); CAS(b2,b3); CAS(b4,b5); CAS(b6,b7);
        CAS(b0,b2); CAS(b1,b3); CAS(b4,b6); CAS(b5,b7);
        CAS(b1,b2); CAS(b5,b6);
        CAS(b0,b4); CAS(b1,b5); CAS(b2,b6); CAS(b3,b7);
        CAS(b2,b4); CAS(b3,b5);
        CAS(b1,b2); CAS(b3,b4); CAS(b5,b6);
        s_thr[lr] = (row0 + lr < n) ? b3 : INFINITY;   // ascending[3] = 5th largest
    }
    __syncthreads();
    float thr[RPT];
    #pragma unroll
    for (int r = 0; r < RPT; ++r) thr[r] = s_thr[g + 8*r];
    __syncthreads();

    int*   s_cnt = (int*)scratch;             // [72]
    float* s_cv  = scratch + KROWS;           // [72][CAP]
    int*   s_cj  = (int*)(scratch + KROWS + KROWS*CAP); // [72][CAP]
    if (threadIdx.x < KROWS) s_cnt[threadIdx.x] = 0;
    __syncthreads();

    // ---- pass 2: append candidates >= thr (identical fma order -> exact bits) ----
    #pragma unroll 2
    for (int j = seg; j < n; j += SEGS) {
        float2 x01 = s_x01[j];
        float  xz  = s_x2[j];
        #pragma unroll
        for (int r = 0; r < RPT; ++r) {
            float d = fmaf(xz,h2[r], fmaf(x01.y,h1[r], x01.x*h0[r]));
            if (!(d < thr[r])) {
                int lr = g + 8*r;
                int p = atomicAdd(&s_cnt[lr], 1);
                if (p < CAP) { s_cv[lr*CAP+p] = d; s_cj[lr*CAP+p] = j; }
            }
        }
    }
    __syncthreads();

    // ---- merge: composite top-5 over ~7 candidates per row ----
    if (threadIdx.x < KROWS) {
        int lr = threadIdx.x, row = row0 + lr;
        if (row < n) {
            float v0=-INFINITY,v1=-INFINITY,v2=-INFINITY,v3=-INFINITY,v4=-INFINITY;
            int i0=0x7fffffff,i1=0x7fffffff,i2=0x7fffffff,i3=0x7fffffff,i4=0x7fffffff;
            int mcnt = s_cnt[lr];
            if (mcnt <= CAP) {
                for (int t = 0; t < mcnt; ++t) {
                    float s = s_cv[lr*CAP + t]; int jj = s_cj[lr*CAP + t];
                    INS5C(s, jj, v0,v1,v2,v3,v4, i0,i1,i2,i3,i4);
                }
            } else {
                // overflow fallback (P ~ 2e-6/row): serial ascending-j rescan
                float ha = h_c[(base+row)*3], hb = h_c[(base+row)*3+1], hc2 = h_c[(base+row)*3+2];
                v0=v1=v2=v3=v4=-INFINITY; i0=i1=i2=i3=i4=0;
                for (int jj = 0; jj < n; ++jj) {
                    float s = fmaf(s_x2[jj],hc2, fmaf(s_x01[jj].y,hb, s_x01[jj].x*ha));
                    INS5(s, jj, v0,v1,v2,v3,v4, i0,i1,i2,i3,i4);
                }
            }
            int o = (base+row)*TOPKN;
            tidx[o+0]=i0; tidx[o+1]=i1; tidx[o+2]=i2; tidx[o+3]=i3; tidx[o+4]=i4;
        }
    }
}

// ---- K3: gather + hsum -> bf16 MFMA GEMM; 512 thr, col-split waves; A out bf16 ----
__global__ __launch_bounds__(512) void k3_gemm1(const float* __restrict__ x_f,
                         const float* __restrict__ h_f,
                         const int* __restrict__ tidx,
                         const unsigned short* __restrict__ Th,
                         const float* __restrict__ bo, unsigned short* __restrict__ A,
                         float* __restrict__ cstats)
{
    __shared__ unsigned short s_ah[64][APAD];
    __shared__ unsigned short s_wh[128][WPAD];
    __shared__ int s_nb[64][TOPKN];
    __shared__ float s_red[256];
    int chunk = blockIdx.y;
    int base  = chunk * FCHUNK;
    int n     = chunk_n(chunk);
    int row0  = blockIdx.x * 64;
    if (row0 >= n) return;

    if (threadIdx.x < 64*TOPKN) {
        int e = threadIdx.x;
        int r = e / TOPKN, k = e % TOPKN;
        int il = row0 + r;
        int nb = 0;
        if (il < n) {
            int p = il*TOPKN + k;             // faithful tidx.T flatten order
            int q, m;
            if (n == FCHUNK) { q = p / FCHUNK; m = p - q*FCHUNK; }
            else             { q = p / NREM;   m = p - q*NREM; }
            nb = tidx[(base + m)*TOPKN + q];
        }
        s_nb[r][k] = nb;
    }
    __syncthreads();

    // gather + hsum (fp32), truncate to bf16 hi plane
    for (int e = threadIdx.x; e < 64*32; e += 512) {
        int r = e >> 5, c4 = e & 31;
        float4 acc4 = make_float4(0.f,0.f,0.f,0.f);
        int gr = row0 + r;
        if (gr < n) {
            acc4 = *(const float4*)&x_f[(base+gr)*CDIM + c4*4];
            #pragma unroll
            for (int k = 0; k < TOPKN; ++k) {
                float4 h4 = *(const float4*)&h_f[(base + s_nb[r][k])*CDIM + c4*4];
                acc4.x += h4.x; acc4.y += h4.y; acc4.z += h4.z; acc4.w += h4.w;
            }
        }
        uint2 ph;
        ph.x = (unsigned)bf16hi(acc4.x) | ((unsigned)bf16hi(acc4.y) << 16);
        ph.y = (unsigned)bf16hi(acc4.z) | ((unsigned)bf16hi(acc4.w) << 16);
        *(uint2*)&s_ah[r][c4*4] = ph;
    }

    int lane = threadIdx.x & 63;
    int w    = threadIdx.x >> 6;          // wave id 0..7
    int wr   = w & 3;                     // row block (16 rows)
    int wc   = w >> 2;                    // col half (64 cols)
    int lr   = lane & 15, lg = lane >> 4;
    float4v acc[4];
    #pragma unroll
    for (int ct = 0; ct < 4; ++ct) acc[ct] = (float4v){0.f,0.f,0.f,0.f};

    for (int ks = 0; ks < 4; ++ks) {
        __syncthreads();
        {   // stage W-hi tile: 4096 ushorts / 512 thr = 1 uint4 each
            int col = threadIdx.x >> 2, q = threadIdx.x & 3;
            *(uint4*)&s_wh[col][q*8] = *(const uint4*)&Th[col*CDIM + ks*32 + q*8];
        }
        __syncthreads();
        short8v a_h = *(const short8v*)&s_ah[wr*16 + lr][ks*32 + lg*8];
        #pragma unroll
        for (int ct = 0; ct < 4; ++ct) {
            short8v b_h = *(const short8v*)&s_wh[(wc*4 + ct)*16 + lr][lg*8];
            acc[ct] = __builtin_amdgcn_mfma_f32_16x16x32_bf16(a_h, b_h, acc[ct], 0,0,0);
        }
    }

    // epilogue + fused per-chunk stats. C/D: col=lane&15, row=(lane>>4)*4+reg
    float ps[4], ps2[4];
    #pragma unroll
    for (int ct = 0; ct < 4; ++ct) { ps[ct] = 0.f; ps2[ct] = 0.f; }
    #pragma unroll
    for (int ct = 0; ct < 4; ++ct) {
        int gcol = (wc*4 + ct)*16 + lr;
        float b = bo[gcol];
        #pragma unroll
        for (int ri = 0; ri < 4; ++ri) {
            int grow = row0 + wr*16 + lg*4 + ri;
            if (grow < n) {
                float v = acc[ct][ri] + b;
                A[(base+grow)*CDIM + gcol] = bf16hi(v);
                ps[ct] += v; ps2[ct] = fmaf(v, v, ps2[ct]);
            }
        }
    }
    #pragma unroll
    for (int ct = 0; ct < 4; ++ct) {          // reduce over lg within wave
        ps[ct]  += __shfl_xor(ps[ct], 16, 64);  ps[ct]  += __shfl_xor(ps[ct], 32, 64);
        ps2[ct] += __shfl_xor(ps2[ct], 16, 64); ps2[ct] += __shfl_xor(ps2[ct], 32, 64);
    }
    __syncthreads();
    if (threadIdx.x < 256) s_red[threadIdx.x] = 0.f;
    __syncthreads();
    if (lane < 16) {
        #pragma unroll
        for (int ct = 0; ct < 4; ++ct) {
            int gcol = (wc*4 + ct)*16 + lane;
            atomicAdd(&s_red[gcol*2],   ps[ct]);
            atomicAdd(&s_red[gcol*2+1], ps2[ct]);
        }
    }
    __syncthreads();
    if (threadIdx.x < 128) {
        atomicAdd(&cstats[chunk*256 + threadIdx.x],       s_red[threadIdx.x*2]);
        atomicAdd(&cstats[chunk*256 + 128 + threadIdx.x], s_red[threadIdx.x*2+1]);
    }
}

// ---- K5: relu(BN_chunk(A_bf16)) -> bf16 MFMA GEMM; 512 thr; fused gstats ----
__global__ __launch_bounds__(512) void k5_gemm2(const unsigned short* __restrict__ A,
                         const unsigned short* __restrict__ Thp,
                         const float* __restrict__ bp, const float* __restrict__ gamma_a,
                         const float* __restrict__ beta_a, const float* __restrict__ cstats,
                         float* __restrict__ Z, float* __restrict__ gstats)
{
    __shared__ unsigned short s_ah[64][APAD];
    __shared__ unsigned short s_wh[128][WPAD];
    __shared__ float s_sc[CDIM], s_sf[CDIM];
    __shared__ float s_red[256];
    int chunk = blockIdx.y;
    int base  = chunk * FCHUNK;
    int n     = chunk_n(chunk);
    int row0  = blockIdx.x * 64;
    if (row0 >= n) return;

    if (threadIdx.x < CDIM) {
        int c = threadIdx.x;
        float inv_n = 1.f / (float)n;
        float mu  = cstats[chunk*256 + c] * inv_n;
        float var = cstats[chunk*256 + 128 + c] * inv_n - mu*mu;
        float sc  = gamma_a[c] * rsqrtf(var + BNEPS);
        s_sc[c] = sc;
        s_sf[c] = beta_a[c] - mu*sc;
    }
    __syncthreads();

    for (int e = threadIdx.x; e < 64*32; e += 512) {
        int r = e >> 5, c4 = e & 31;
        uint2 ph = make_uint2(0u, 0u);
        int gr = row0 + r;
        if (gr < n) {
            uint2 a2 = *(const uint2*)&A[(base+gr)*CDIM + c4*4];
            int c = c4*4;
            float a0 = bf16tof((unsigned short)(a2.x & 0xFFFF));
            float a1 = bf16tof((unsigned short)(a2.x >> 16));
            float a2f = bf16tof((unsigned short)(a2.y & 0xFFFF));
            float a3 = bf16tof((unsigned short)(a2.y >> 16));
            float y0 = fmaxf(fmaf(a0, s_sc[c+0], s_sf[c+0]), 0.f);
            float y1 = fmaxf(fmaf(a1, s_sc[c+1], s_sf[c+1]), 0.f);
            float y2 = fmaxf(fmaf(a2f, s_sc[c+2], s_sf[c+2]), 0.f);
            float y3 = fmaxf(fmaf(a3, s_sc[c+3], s_sf[c+3]), 0.f);
            ph.x = (unsigned)bf16hi(y0) | ((unsigned)bf16hi(y1) << 16);
            ph.y = (unsigned)bf16hi(y2) | ((unsigned)bf16hi(y3) << 16);
        }
        *(uint2*)&s_ah[r][c4*4] = ph;
    }

    int lane = threadIdx.x & 63;
    int w    = threadIdx.x >> 6;
    int wr   = w & 3;
    int wc   = w >> 2;
    int lr   = lane & 15, lg = lane >> 4;
    float4v acc[4];
    #pragma unroll
    for (int ct = 0; ct < 4; ++ct) acc[ct] = (float4v){0.f,0.f,0.f,0.f};

    for (int ks = 0; ks < 4; ++ks) {
        __syncthreads();
        {
            int col = threadIdx.x >> 2, q = threadIdx.x & 3;
            *(uint4*)&s_wh[col][q*8] = *(const uint4*)&Thp[col*CDIM + ks*32 + q*8];
        }
        __syncthreads();
        short8v a_h = *(const short8v*)&s_ah[wr*16 + lr][ks*32 + lg*8];
        #pragma unroll
        for (int ct = 0; ct < 4; ++ct) {
            short8v b_h = *(const short8v*)&s_wh[(wc*4 + ct)*16 + lr][lg*8];
            acc[ct] = __builtin_amdgcn_mfma_f32_16x16x32_bf16(a_h, b_h, acc[ct], 0,0,0);
        }
    }

    float ps[4], ps2[4];
    #pragma unroll
    for (int ct = 0; ct < 4; ++ct) { ps[ct] = 0.f; ps2[ct] = 0.f; }
    #pragma unroll
    for (int ct = 0; ct < 4; ++ct) {
        int gcol = (wc*4 + ct)*16 + lr;
        float b = bp[gcol];
        #pragma unroll
        for (int ri = 0; ri < 4; ++ri) {
            int grow = row0 + wr*16 + lg*4 + ri;
            if (grow < n) {
                float v = acc[ct][ri] + b;
                Z[(base+grow)*CDIM + gcol] = v;
                ps[ct] += v; ps2[ct] = fmaf(v, v, ps2[ct]);
            }
        }
    }
    #pragma unroll
    for (int ct = 0; ct < 4; ++ct) {
        ps[ct]  += __shfl_xor(ps[ct], 16, 64);  ps[ct]  += __shfl_xor(ps[ct], 32, 64);
        ps2[ct] += __shfl_xor(ps2[ct], 16, 64); ps2[ct] += __shfl_xor(ps2[ct], 32, 64);
    }
    __syncthreads();
    if (threadIdx.x < 256) s_red[threadIdx.x] = 0.f;
    __syncthreads();
    if (lane < 16) {
        #pragma unroll
        for (int ct = 0; ct < 4; ++ct) {
            int gcol = (wc*4 + ct)*16 + lane;
            atomicAdd(&s_red[gcol*2],   ps[ct]);
            atomicAdd(&s_red[gcol*2+1], ps2[ct]);
        }
    }
    __syncthreads();
    if (threadIdx.x < 128) {
        atomicAdd(&gstats[threadIdx.x],       s_red[threadIdx.x*2]);
        atomicAdd(&gstats[128 + threadIdx.x], s_red[threadIdx.x*2+1]);
    }
}

// ---------------- K7: final BN + ReLU in place (float4) ----------------
__global__ void k7_final(float* __restrict__ Z, const float* __restrict__ gstats,
                         const float* __restrict__ gamma_p, const float* __restrict__ beta_p)
{
    __shared__ float s_sc[CDIM], s_sf[CDIM];
    if (threadIdx.x < CDIM) {
        int c = threadIdx.x;
        const float inv_n = 1.f / (float)NTOT;
        float mu  = gstats[c] * inv_n;
        float var = gstats[128 + c] * inv_n - mu*mu;
        float sc  = gamma_p[c] * rsqrtf(var + BNEPS);
        s_sc[c] = sc;
        s_sf[c] = beta_p[c] - mu*sc;
    }
    __syncthreads();
    int i4 = blockIdx.x * blockDim.x + threadIdx.x;
    if (i4 >= NTOT*32) return;
    float4 z = ((const float4*)Z)[i4];
    int c = (i4 & 31) * 4;
    z.x = fmaxf(fmaf(z.x, s_sc[c+0], s_sf[c+0]), 0.f);
    z.y = fmaxf(fmaf(z.y, s_sc[c+1], s_sf[c+1]), 0.f);
    z.z = fmaxf(fmaf(z.z, s_sc[c+2], s_sf[c+2]), 0.f);
    z.w = fmaxf(fmaf(z.w, s_sc[c+3], s_sf[c+3]), 0.f);
    ((float4*)Z)[i4] = z;
}

extern "C" void kernel_launch(void* const* d_in, const int* in_sizes, int n_in,
                              void* d_out, int out_size, void* d_ws, size_t ws_size,
                              hipStream_t stream)
{
    (void)in_sizes; (void)n_in; (void)out_size; (void)ws_size;
    const float* h_f  = (const float*)d_in[0];
    const float* x_f  = (const float*)d_in[1];
    const float* x_c  = (const float*)d_in[2];
    const float* h_c  = (const float*)d_in[3];
    const float* Wv   = (const float*)d_in[6];
    const float* Wo   = (const float*)d_in[7];
    const float* bo   = (const float*)d_in[8];
    const float* ga   = (const float*)d_in[9];
    const float* ba   = (const float*)d_in[10];
    const float* Wp   = (const float*)d_in[11];
    const float* bp   = (const float*)d_in[12];
    const float* gp   = (const float*)d_in[13];
    const float* betp = (const float*)d_in[14];

    char*  ws     = (char*)d_ws;
    unsigned short* Th  = (unsigned short*)ws;             // 32768 B (W1T)
    unsigned short* Thp = (unsigned short*)(ws + 32768);   // 32768 B (WpT)
    float* cstats = (float*)(ws + 65536);                  // 19456 B
    float* gstats = (float*)(ws + 65536 + 19456);          // 1024 B
    int*   tidx   = (int*)(ws + 65536 + 20480);            // 1,000,000 B
    unsigned short* A = (unsigned short*)(ws + 65536 + 20480 + 1000000); // 12.8 MB (bf16)
    float* Z      = (float*)d_out;

    hipMemsetAsync(ws + 65536, 0, 20480, stream);          // zero cstats + gstats

    k1_both  <<<dim3(2*CDIM),      dim3(CDIM), 0, stream>>>(Wv, Wo, Wp, Th, Thp);
    k2_topk  <<<dim3(KBLK, NCHUNKS), dim3(512), 0, stream>>>(x_c, h_c, tidx);
    k3_gemm1 <<<dim3(43, NCHUNKS), dim3(512),  0, stream>>>(x_f, h_f, tidx, Th, bo, A, cstats);
    k5_gemm2 <<<dim3(43, NCHUNKS), dim3(512),  0, stream>>>(A, Thp, bp, ga, ba, cstats, Z, gstats);
    k7_final <<<dim3((NTOT*32 + 255)/256), dim3(256), 0, stream>>>(Z, gstats, gp, betp);
}

// Round 28
// 132.971 us; speedup vs baseline: 2.3537x; 1.0202x over previous
//
#include <hip/hip_runtime.h>
#include <hip/hip_bf16.h>
#include <math.h>

#define NTOT    50000
#define CDIM    128
#define FCHUNK  2714
#define MCH     18
#define NREM    (NTOT - MCH*FCHUNK)   /* 1148 */
#define NCHUNKS 19
#define TOPKN   5
#define INNERD  512
#define BNEPS   1e-5f
#define SEGS    64
#define RPT     9     /* rows per thread (512-thread k2, 64 segs, 72-row tile) */
#define KROWS   72    /* rows per k2 block */
#define KBLK    38    /* ceil(2714/72) */
#define CAP     25
#define APAD    136   /* ushort stride, 272B = 17*16 -> b128-aligned rows */
#define WPAD    40    /* ushort stride, 80B = 5*16  -> b128-aligned rows */

typedef __attribute__((ext_vector_type(8))) short short8v;   // 8 bf16 = 4 VGPR
typedef __attribute__((ext_vector_type(4))) float float4v;   // MFMA acc

static __device__ __forceinline__ int chunk_n(int chunk) {
    return (chunk < MCH) ? FCHUNK : NREM;
}

static __device__ __forceinline__ unsigned short bf16hi(float v) {
    return (unsigned short)(__float_as_uint(v) >> 16);   // truncation
}

static __device__ __forceinline__ float bf16tof(unsigned short u) {
    return __uint_as_float((unsigned)u << 16);
}

// strict-> sorted insert == lax.top_k stable tie-break (ascending-j stream)
#define INS5(s, jj, V0,V1,V2,V3,V4,I0,I1,I2,I3,I4) \
    if (s > V4) { \
        if (s > V0)      { V4=V3;I4=I3; V3=V2;I3=I2; V2=V1;I2=I1; V1=V0;I1=I0; V0=s;I0=jj; } \
        else if (s > V1) { V4=V3;I4=I3; V3=V2;I3=I2; V2=V1;I2=I1; V1=s;I1=jj; } \
        else if (s > V2) { V4=V3;I4=I3; V3=V2;I3=I2; V2=s;I2=jj; } \
        else if (s > V3) { V4=V3;I4=I3; V3=s;I3=jj; } \
        else             { V4=s;I4=jj; } \
    }

// composite (val desc, idx asc) insert — order-independent == stable top-k
#define INS5C(s, jj, V0,V1,V2,V3,V4,I0,I1,I2,I3,I4) \
    if ((s > V4) || (s == V4 && jj < I4)) { \
        if ((s > V0) || (s == V0 && jj < I0))      { V4=V3;I4=I3; V3=V2;I3=I2; V2=V1;I2=I1; V1=V0;I1=I0; V0=s;I0=jj; } \
        else if ((s > V1) || (s == V1 && jj < I1)) { V4=V3;I4=I3; V3=V2;I3=I2; V2=V1;I2=I1; V1=s;I1=jj; } \
        else if ((s > V2) || (s == V2 && jj < I2)) { V4=V3;I4=I3; V3=V2;I3=I2; V2=s;I2=jj; } \
        else if ((s > V3) || (s == V3 && jj < I3)) { V4=V3;I4=I3; V3=s;I3=jj; } \
        else                                        { V4=s;I4=jj; } \
    }

#define CAS(x, y) { float lo_ = fminf(x, y), hi_ = fmaxf(x, y); x = lo_; y = hi_; }

// ---- K1: blocks 0..127: W1=Wv@Wo row -> Th; blocks 128..255: Wp row -> Thp ----
__global__ void k1_both(const float* __restrict__ Wv, const float* __restrict__ Wo,
                        const float* __restrict__ Wp,
                        unsigned short* __restrict__ Th, unsigned short* __restrict__ Thp)
{
    __shared__ float s_wv[INNERD];
    if (blockIdx.x < CDIM) {
        int r = blockIdx.x;
        for (int t = threadIdx.x; t < INNERD; t += blockDim.x) s_wv[t] = Wv[r*INNERD + t];
        __syncthreads();
        int c = threadIdx.x;
        float acc = 0.f;
        #pragma unroll 8
        for (int k = 0; k < INNERD; ++k) acc = fmaf(s_wv[k], Wo[k*CDIM + c], acc);
        Th[c*CDIM + r] = bf16hi(acc);    // transposed: [col][k]
    } else {
        int r = blockIdx.x - CDIM, c = threadIdx.x;
        Thp[c*CDIM + r] = bf16hi(Wp[r*CDIM + c]);
    }
}

// --- K2: top-5, 512 threads; 64 residue classes, 9 rows/thread, 72-row tile ---
__global__ __launch_bounds__(512) void k2_topk(const float* __restrict__ x_c,
                                               const float* __restrict__ h_c,
                                               int* __restrict__ tidx)
{
    __shared__ float2 s_x01[FCHUNK];
    __shared__ float  s_x2[FCHUNK];
    __shared__ float  scratch[4752];          // A: segmax[72][65]+thr[72] | B: cnt/cv/cj
    int chunk = blockIdx.y;
    int base  = chunk * FCHUNK;
    int n     = chunk_n(chunk);
    int row0  = blockIdx.x * KROWS;
    if (row0 >= n) return;

    for (int e = threadIdx.x; e < n; e += 512) {
        s_x01[e] = make_float2(x_c[(base+e)*3], x_c[(base+e)*3 + 1]);
        s_x2[e]  = x_c[(base+e)*3 + 2];
    }
    __syncthreads();

    int seg = threadIdx.x & 63;               // residue class: j = seg + 64t
    int g   = threadIdx.x >> 6;               // 0..7; rows g, g+8, ..., g+64

    float h0[RPT], h1[RPT], h2[RPT];
    #pragma unroll
    for (int r = 0; r < RPT; ++r) {
        int row = row0 + g + 8*r;
        bool v = row < n;
        h0[r] = v ? h_c[(base+row)*3  ] : 0.f;
        h1[r] = v ? h_c[(base+row)*3+1] : 0.f;
        h2[r] = v ? h_c[(base+row)*3+2] : 0.f;
    }

    // ---- pass 1: branchless residue-class maxes, 9 rows per x-read ----
    float m[RPT];
    #pragma unroll
    for (int r = 0; r < RPT; ++r) m[r] = -INFINITY;
    #pragma unroll 2
    for (int j = seg; j < n; j += SEGS) {
        float2 x01 = s_x01[j];
        float  xz  = s_x2[j];
        #pragma unroll
        for (int r = 0; r < RPT; ++r)
            m[r] = fmaxf(m[r], fmaf(xz,h2[r], fmaf(x01.y,h1[r], x01.x*h0[r])));
    }
    float* s_segmax = scratch;                // [72][65]
    float* s_thr    = scratch + KROWS*65;     // [72]
    #pragma unroll
    for (int r = 0; r < RPT; ++r) s_segmax[(g+8*r)*65 + seg] = m[r];
    __syncthreads();

    // ---- threshold: 5th largest of 8 supersegments-of-8 (T <= v5) ----
    if (threadIdx.x < KROWS) {
        int lr = threadIdx.x;
        const float* sm = &s_segmax[lr*65];
        float b[8];
        #pragma unroll
        for (int ss = 0; ss < 8; ++ss) {
            float m0 = fmaxf(fmaxf(sm[ss*8+0],sm[ss*8+1]), fmaxf(sm[ss*8+2],sm[ss*8+3]));
            float m1 = fmaxf(fmaxf(sm[ss*8+4],sm[ss*8+5]), fmaxf(sm[ss*8+6],sm[ss*8+7]));
            b[ss] = fmaxf(m0, m1);
        }
        float b0=b[0],b1=b[1],b2=b[2],b3=b[3],b4=b[4],b5=b[5],b6=b[6],b7=b[7];
        CAS(b0,b1); CAS(b2,b3); CAS(b4,b5); CAS(b6,b7);
        CAS(b0,b2); CAS(b1,b3); CAS(b4,b6); CAS(b5,b7);
        CAS(b1,b2); CAS(b5,b6);
        CAS(b0,b4); CAS(b1,b5); CAS(b2,b6); CAS(b3,b7);
        CAS(b2,b4); CAS(b3,b5);
        CAS(b1,b2); CAS(b3,b4); CAS(b5,b6);
        s_thr[lr] = (row0 + lr < n) ? b3 : INFINITY;   // ascending[3] = 5th largest
    }
    __syncthreads();
    float thr[RPT];
    #pragma unroll
    for (int r = 0; r < RPT; ++r) thr[r] = s_thr[g + 8*r];
    __syncthreads();

    int*   s_cnt = (int*)scratch;             // [72]
    float* s_cv  = scratch + KROWS;           // [72][CAP]
    int*   s_cj  = (int*)(scratch + KROWS + KROWS*CAP); // [72][CAP]
    if (threadIdx.x < KROWS) s_cnt[threadIdx.x] = 0;
    __syncthreads();

    // ---- pass 2: append candidates >= thr (identical fma order -> exact bits) ----
    #pragma unroll 2
    for (int j = seg; j < n; j += SEGS) {
        float2 x01 = s_x01[j];
        float  xz  = s_x2[j];
        #pragma unroll
        for (int r = 0; r < RPT; ++r) {
            float d = fmaf(xz,h2[r], fmaf(x01.y,h1[r], x01.x*h0[r]));
            if (!(d < thr[r])) {
                int lr = g + 8*r;
                int p = atomicAdd(&s_cnt[lr], 1);
                if (p < CAP) { s_cv[lr*CAP+p] = d; s_cj[lr*CAP+p] = j; }
            }
        }
    }
    __syncthreads();

    // ---- merge: composite top-5 over ~7 candidates per row ----
    if (threadIdx.x < KROWS) {
        int lr = threadIdx.x, row = row0 + lr;
        if (row < n) {
            float v0=-INFINITY,v1=-INFINITY,v2=-INFINITY,v3=-INFINITY,v4=-INFINITY;
            int i0=0x7fffffff,i1=0x7fffffff,i2=0x7fffffff,i3=0x7fffffff,i4=0x7fffffff;
            int mcnt = s_cnt[lr];
            if (mcnt <= CAP) {
                for (int t = 0; t < mcnt; ++t) {
                    float s = s_cv[lr*CAP + t]; int jj = s_cj[lr*CAP + t];
                    INS5C(s, jj, v0,v1,v2,v3,v4, i0,i1,i2,i3,i4);
                }
            } else {
                // overflow fallback (P ~ 2e-6/row): serial ascending-j rescan
                float ha = h_c[(base+row)*3], hb = h_c[(base+row)*3+1], hc2 = h_c[(base+row)*3+2];
                v0=v1=v2=v3=v4=-INFINITY; i0=i1=i2=i3=i4=0;
                for (int jj = 0; jj < n; ++jj) {
                    float s = fmaf(s_x2[jj],hc2, fmaf(s_x01[jj].y,hb, s_x01[jj].x*ha));
                    INS5(s, jj, v0,v1,v2,v3,v4, i0,i1,i2,i3,i4);
                }
            }
            int o = (base+row)*TOPKN;
            tidx[o+0]=i0; tidx[o+1]=i1; tidx[o+2]=i2; tidx[o+3]=i3; tidx[o+4]=i4;
        }
    }
}

// ---- K3: gather + hsum -> bf16 MFMA GEMM; 512 thr, col-split waves; A out bf16 ----
__global__ __launch_bounds__(512) void k3_gemm1(const float* __restrict__ x_f,
                         const float* __restrict__ h_f,
                         const int* __restrict__ tidx,
                         const unsigned short* __restrict__ Th,
                         const float* __restrict__ bo, unsigned short* __restrict__ A,
                         float* __restrict__ cstats)
{
    __shared__ unsigned short s_ah[64][APAD];
    __shared__ unsigned short s_wh[128][WPAD];
    __shared__ int s_nb[64][TOPKN];
    __shared__ float s_red[256];
    int chunk = blockIdx.y;
    int base  = chunk * FCHUNK;
    int n     = chunk_n(chunk);
    int row0  = blockIdx.x * 64;
    if (row0 >= n) return;

    if (threadIdx.x < 64*TOPKN) {
        int e = threadIdx.x;
        int r = e / TOPKN, k = e % TOPKN;
        int il = row0 + r;
        int nb = 0;
        if (il < n) {
            int p = il*TOPKN + k;             // faithful tidx.T flatten order
            int q, m;
            if (n == FCHUNK) { q = p / FCHUNK; m = p - q*FCHUNK; }
            else             { q = p / NREM;   m = p - q*NREM; }
            nb = tidx[(base + m)*TOPKN + q];
        }
        s_nb[r][k] = nb;
    }
    __syncthreads();

    // gather + hsum (fp32), truncate to bf16 hi plane
    for (int e = threadIdx.x; e < 64*32; e += 512) {
        int r = e >> 5, c4 = e & 31;
        float4 acc4 = make_float4(0.f,0.f,0.f,0.f);
        int gr = row0 + r;
        if (gr < n) {
            acc4 = *(const float4*)&x_f[(base+gr)*CDIM + c4*4];
            #pragma unroll
            for (int k = 0; k < TOPKN; ++k) {
                float4 h4 = *(const float4*)&h_f[(base + s_nb[r][k])*CDIM + c4*4];
                acc4.x += h4.x; acc4.y += h4.y; acc4.z += h4.z; acc4.w += h4.w;
            }
        }
        uint2 ph;
        ph.x = (unsigned)bf16hi(acc4.x) | ((unsigned)bf16hi(acc4.y) << 16);
        ph.y = (unsigned)bf16hi(acc4.z) | ((unsigned)bf16hi(acc4.w) << 16);
        *(uint2*)&s_ah[r][c4*4] = ph;
    }

    int lane = threadIdx.x & 63;
    int w    = threadIdx.x >> 6;          // wave id 0..7
    int wr   = w & 3;                     // row block (16 rows)
    int wc   = w >> 2;                    // col half (64 cols)
    int lr   = lane & 15, lg = lane >> 4;
    float4v acc[4];
    #pragma unroll
    for (int ct = 0; ct < 4; ++ct) acc[ct] = (float4v){0.f,0.f,0.f,0.f};

    for (int ks = 0; ks < 4; ++ks) {
        __syncthreads();
        {   // stage W-hi tile: 4096 ushorts / 512 thr = 1 uint4 each
            int col = threadIdx.x >> 2, q = threadIdx.x & 3;
            *(uint4*)&s_wh[col][q*8] = *(const uint4*)&Th[col*CDIM + ks*32 + q*8];
        }
        __syncthreads();
        short8v a_h = *(const short8v*)&s_ah[wr*16 + lr][ks*32 + lg*8];
        #pragma unroll
        for (int ct = 0; ct < 4; ++ct) {
            short8v b_h = *(const short8v*)&s_wh[(wc*4 + ct)*16 + lr][lg*8];
            acc[ct] = __builtin_amdgcn_mfma_f32_16x16x32_bf16(a_h, b_h, acc[ct], 0,0,0);
        }
    }

    // epilogue + fused per-chunk stats. C/D: col=lane&15, row=(lane>>4)*4+reg
    float ps[4], ps2[4];
    #pragma unroll
    for (int ct = 0; ct < 4; ++ct) { ps[ct] = 0.f; ps2[ct] = 0.f; }
    #pragma unroll
    for (int ct = 0; ct < 4; ++ct) {
        int gcol = (wc*4 + ct)*16 + lr;
        float b = bo[gcol];
        #pragma unroll
        for (int ri = 0; ri < 4; ++ri) {
            int grow = row0 + wr*16 + lg*4 + ri;
            if (grow < n) {
                float v = acc[ct][ri] + b;
                A[(base+grow)*CDIM + gcol] = bf16hi(v);
                ps[ct] += v; ps2[ct] = fmaf(v, v, ps2[ct]);
            }
        }
    }
    #pragma unroll
    for (int ct = 0; ct < 4; ++ct) {          // reduce over lg within wave
        ps[ct]  += __shfl_xor(ps[ct], 16, 64);  ps[ct]  += __shfl_xor(ps[ct], 32, 64);
        ps2[ct] += __shfl_xor(ps2[ct], 16, 64); ps2[ct] += __shfl_xor(ps2[ct], 32, 64);
    }
    __syncthreads();
    if (threadIdx.x < 256) s_red[threadIdx.x] = 0.f;
    __syncthreads();
    if (lane < 16) {
        #pragma unroll
        for (int ct = 0; ct < 4; ++ct) {
            int gcol = (wc*4 + ct)*16 + lane;
            atomicAdd(&s_red[gcol*2],   ps[ct]);
            atomicAdd(&s_red[gcol*2+1], ps2[ct]);
        }
    }
    __syncthreads();
    if (threadIdx.x < 128) {
        atomicAdd(&cstats[chunk*256 + threadIdx.x],       s_red[threadIdx.x*2]);
        atomicAdd(&cstats[chunk*256 + 128 + threadIdx.x], s_red[threadIdx.x*2+1]);
    }
}

// ---- K5: relu(BN_chunk(A_bf16)) -> bf16 MFMA GEMM; writes pre-BN2 bf16 IN-PLACE over A ----
__global__ __launch_bounds__(512) void k5_gemm2(unsigned short* __restrict__ A,
                         const unsigned short* __restrict__ Thp,
                         const float* __restrict__ bp, const float* __restrict__ gamma_a,
                         const float* __restrict__ beta_a, const float* __restrict__ cstats,
                         float* __restrict__ gstats)
{
    __shared__ unsigned short s_ah[64][APAD];
    __shared__ unsigned short s_wh[128][WPAD];
    __shared__ float s_sc[CDIM], s_sf[CDIM];
    __shared__ float s_red[256];
    int chunk = blockIdx.y;
    int base  = chunk * FCHUNK;
    int n     = chunk_n(chunk);
    int row0  = blockIdx.x * 64;
    if (row0 >= n) return;

    if (threadIdx.x < CDIM) {
        int c = threadIdx.x;
        float inv_n = 1.f / (float)n;
        float mu  = cstats[chunk*256 + c] * inv_n;
        float var = cstats[chunk*256 + 128 + c] * inv_n - mu*mu;
        float sc  = gamma_a[c] * rsqrtf(var + BNEPS);
        s_sc[c] = sc;
        s_sf[c] = beta_a[c] - mu*sc;
    }
    __syncthreads();

    for (int e = threadIdx.x; e < 64*32; e += 512) {
        int r = e >> 5, c4 = e & 31;
        uint2 ph = make_uint2(0u, 0u);
        int gr = row0 + r;
        if (gr < n) {
            uint2 a2 = *(const uint2*)&A[(base+gr)*CDIM + c4*4];
            int c = c4*4;
            float a0 = bf16tof((unsigned short)(a2.x & 0xFFFF));
            float a1 = bf16tof((unsigned short)(a2.x >> 16));
            float a2f = bf16tof((unsigned short)(a2.y & 0xFFFF));
            float a3 = bf16tof((unsigned short)(a2.y >> 16));
            float y0 = fmaxf(fmaf(a0, s_sc[c+0], s_sf[c+0]), 0.f);
            float y1 = fmaxf(fmaf(a1, s_sc[c+1], s_sf[c+1]), 0.f);
            float y2 = fmaxf(fmaf(a2f, s_sc[c+2], s_sf[c+2]), 0.f);
            float y3 = fmaxf(fmaf(a3, s_sc[c+3], s_sf[c+3]), 0.f);
            ph.x = (unsigned)bf16hi(y0) | ((unsigned)bf16hi(y1) << 16);
            ph.y = (unsigned)bf16hi(y2) | ((unsigned)bf16hi(y3) << 16);
        }
        *(uint2*)&s_ah[r][c4*4] = ph;
    }

    int lane = threadIdx.x & 63;
    int w    = threadIdx.x >> 6;
    int wr   = w & 3;
    int wc   = w >> 2;
    int lr   = lane & 15, lg = lane >> 4;
    float4v acc[4];
    #pragma unroll
    for (int ct = 0; ct < 4; ++ct) acc[ct] = (float4v){0.f,0.f,0.f,0.f};

    for (int ks = 0; ks < 4; ++ks) {
        __syncthreads();
        {
            int col = threadIdx.x >> 2, q = threadIdx.x & 3;
            *(uint4*)&s_wh[col][q*8] = *(const uint4*)&Thp[col*CDIM + ks*32 + q*8];
        }
        __syncthreads();
        short8v a_h = *(const short8v*)&s_ah[wr*16 + lr][ks*32 + lg*8];
        #pragma unroll
        for (int ct = 0; ct < 4; ++ct) {
            short8v b_h = *(const short8v*)&s_wh[(wc*4 + ct)*16 + lr][lg*8];
            acc[ct] = __builtin_amdgcn_mfma_f32_16x16x32_bf16(a_h, b_h, acc[ct], 0,0,0);
        }
    }

    float ps[4], ps2[4];
    #pragma unroll
    for (int ct = 0; ct < 4; ++ct) { ps[ct] = 0.f; ps2[ct] = 0.f; }
    #pragma unroll
    for (int ct = 0; ct < 4; ++ct) {
        int gcol = (wc*4 + ct)*16 + lr;
        float b = bp[gcol];
        #pragma unroll
        for (int ri = 0; ri < 4; ++ri) {
            int grow = row0 + wr*16 + lg*4 + ri;
            if (grow < n) {
                float v = acc[ct][ri] + b;
                A[(base+grow)*CDIM + gcol] = bf16hi(v);   // in-place pre-BN2 bf16
                ps[ct] += v; ps2[ct] = fmaf(v, v, ps2[ct]);
            }
        }
    }
    #pragma unroll
    for (int ct = 0; ct < 4; ++ct) {
        ps[ct]  += __shfl_xor(ps[ct], 16, 64);  ps[ct]  += __shfl_xor(ps[ct], 32, 64);
        ps2[ct] += __shfl_xor(ps2[ct], 16, 64); ps2[ct] += __shfl_xor(ps2[ct], 32, 64);
    }
    __syncthreads();
    if (threadIdx.x < 256) s_red[threadIdx.x] = 0.f;
    __syncthreads();
    if (lane < 16) {
        #pragma unroll
        for (int ct = 0; ct < 4; ++ct) {
            int gcol = (wc*4 + ct)*16 + lane;
            atomicAdd(&s_red[gcol*2],   ps[ct]);
            atomicAdd(&s_red[gcol*2+1], ps2[ct]);
        }
    }
    __syncthreads();
    if (threadIdx.x < 128) {
        atomicAdd(&gstats[threadIdx.x],       s_red[threadIdx.x*2]);
        atomicAdd(&gstats[128 + threadIdx.x], s_red[threadIdx.x*2+1]);
    }
}

// ---- K7: final BN + ReLU: read pre-BN2 bf16 (A), write f32 d_out ----
__global__ void k7_final(const unsigned short* __restrict__ Zb, float* __restrict__ Z,
                         const float* __restrict__ gstats,
                         const float* __restrict__ gamma_p, const float* __restrict__ beta_p)
{
    __shared__ float s_sc[CDIM], s_sf[CDIM];
    if (threadIdx.x < CDIM) {
        int c = threadIdx.x;
        const float inv_n = 1.f / (float)NTOT;
        float mu  = gstats[c] * inv_n;
        float var = gstats[128 + c] * inv_n - mu*mu;
        float sc  = gamma_p[c] * rsqrtf(var + BNEPS);
        s_sc[c] = sc;
        s_sf[c] = beta_p[c] - mu*sc;
    }
    __syncthreads();
    int i4 = blockIdx.x * blockDim.x + threadIdx.x;
    if (i4 >= NTOT*32) return;
    uint2 a2 = *(const uint2*)&Zb[i4*4];
    int c = (i4 & 31) * 4;
    float4 z;
    z.x = fmaxf(fmaf(bf16tof((unsigned short)(a2.x & 0xFFFF)), s_sc[c+0], s_sf[c+0]), 0.f);
    z.y = fmaxf(fmaf(bf16tof((unsigned short)(a2.x >> 16)),    s_sc[c+1], s_sf[c+1]), 0.f);
    z.z = fmaxf(fmaf(bf16tof((unsigned short)(a2.y & 0xFFFF)), s_sc[c+2], s_sf[c+2]), 0.f);
    z.w = fmaxf(fmaf(bf16tof((unsigned short)(a2.y >> 16)),    s_sc[c+3], s_sf[c+3]), 0.f);
    ((float4*)Z)[i4] = z;
}

extern "C" void kernel_launch(void* const* d_in, const int* in_sizes, int n_in,
                              void* d_out, int out_size, void* d_ws, size_t ws_size,
                              hipStream_t stream)
{
    (void)in_sizes; (void)n_in; (void)out_size; (void)ws_size;
    const float* h_f  = (const float*)d_in[0];
    const float* x_f  = (const float*)d_in[1];
    const float* x_c  = (const float*)d_in[2];
    const float* h_c  = (const float*)d_in[3];
    const float* Wv   = (const float*)d_in[6];
    const float* Wo   = (const float*)d_in[7];
    const float* bo   = (const float*)d_in[8];
    const float* ga   = (const float*)d_in[9];
    const float* ba   = (const float*)d_in[10];
    const float* Wp   = (const float*)d_in[11];
    const float* bp   = (const float*)d_in[12];
    const float* gp   = (const float*)d_in[13];
    const float* betp = (const float*)d_in[14];

    char*  ws     = (char*)d_ws;
    unsigned short* Th  = (unsigned short*)ws;             // 32768 B (W1T)
    unsigned short* Thp = (unsigned short*)(ws + 32768);   // 32768 B (WpT)
    float* cstats = (float*)(ws + 65536);                  // 19456 B
    float* gstats = (float*)(ws + 65536 + 19456);          // 1024 B
    int*   tidx   = (int*)(ws + 65536 + 20480);            // 1,000,000 B
    unsigned short* A = (unsigned short*)(ws + 65536 + 20480 + 1000000); // 12.8 MB (bf16)
    float* Z      = (float*)d_out;

    hipMemsetAsync(ws + 65536, 0, 20480, stream);          // zero cstats + gstats

    k1_both  <<<dim3(2*CDIM),      dim3(CDIM), 0, stream>>>(Wv, Wo, Wp, Th, Thp);
    k2_topk  <<<dim3(KBLK, NCHUNKS), dim3(512), 0, stream>>>(x_c, h_c, tidx);
    k3_gemm1 <<<dim3(43, NCHUNKS), dim3(512),  0, stream>>>(x_f, h_f, tidx, Th, bo, A, cstats);
    k5_gemm2 <<<dim3(43, NCHUNKS), dim3(512),  0, stream>>>(A, Thp, bp, ga, ba, cstats, gstats);
    k7_final <<<dim3((NTOT*32 + 255)/256), dim3(256), 0, stream>>>(A, Z, gstats, gp, betp);
}